// Round 13
// baseline (143.205 us; speedup 1.0000x reference)
//
#include <hip/hip_runtime.h>
#include <hip/hip_bf16.h>

// ---------------------------------------------------------------------------
// GraphSAGE 2-layer forward.
//   h   = relu( mean_agg(x) @ W1_l + b1 + x @ W1_r )
//   out =       mean_agg(h) @ W2_l + b2 + h @ W2_r
// agg(x)@W == agg(x@W): transform-then-aggregate. Biases folded into the
// GEMM epilogue of the root term (q = x@W1_r + b1, r = h@W2_r + b2).
// bf16 MFMA GEMMs; bf16 gather buffers (p,g) and addends (q,r); fp32 out.
// CSR build with ZERO global atomics (NSTRIPE=32):
//   D1 hist+wt (512 thr): packed 2xushort LDS hist; range-0 blocks also
//      emit packed edges (src16|dst16, 4B/edge) so later passes read half
//      the bytes; weight-transpose blocks backfill.
//   D2 scan16: cnt[n] = sum_j hist, block scan -> row_start.
//   D3 add_off_base: global prefix; absolute cursors (unpacked) to cur.
//   D4 scatter+GEMM1 (512 thr): scatter blocks first (cursors->LDS via int4,
//      LDS-atomic pos, plain stores, blockIdx&7==range -> XCD-local);
//      GEMM-1 blocks (128 rows, 8 waves) backfill.
// Aggregation: 4 nodes/wave, 16 lanes/node, 16B/lane, 8-deep gather unroll.
// ---------------------------------------------------------------------------

typedef __attribute__((ext_vector_type(8))) short bf16x8;
typedef __attribute__((ext_vector_type(4))) float f32x4;

static __device__ __forceinline__ float bf_lo(unsigned u) {
    u <<= 16; return __builtin_bit_cast(float, u);
}
static __device__ __forceinline__ float bf_hi(unsigned u) {
    u &= 0xffff0000u; return __builtin_bit_cast(float, u);
}
static __device__ __forceinline__ unsigned short f2bf(float f) {
    __hip_bfloat16 b = __float2bfloat16(f);
    return __builtin_bit_cast(unsigned short, b);
}
static __device__ __forceinline__ unsigned packbf(float lo, float hi) {
    return (unsigned)f2bf(lo) | ((unsigned)f2bf(hi) << 16);
}

#define NRANGE   8
#define RANGE_W  6250      // N == 8*6250 exactly
#define PACKED_W 3125      // RANGE_W/2, two ushort counts per int
#define NSTRIPE  32
#define NHIST    (NRANGE * NSTRIPE)   // 256

static __device__ __forceinline__ int stripe_len(int E) {
    return ((E / NSTRIPE) + 3) & ~3;  // multiple of 4 for int4 alignment
}

// ---------------- MFMA dual GEMM body ----------------
// A[M][128] row-major (fp32 if A_F32 else bf16); WTl/WTr[NC][128] bf16 (=W^T).
// Pl = A@Wl (bf16), Qr = A@Wr + bias (bf16). One wave = 16 output rows;
// WPB waves per block. mfma_f32_16x16x32_bf16: A lane l -> row l&15,
// k=(l>>4)*8+j; B lane l -> col l&15, same k; D: col=lane&15, row=(lane>>4)*4+reg.

template <int NC, bool A_F32, int WPB>
static __device__ __forceinline__ void gemm_body(
    int bid, int tid, const void* __restrict__ Av,
    const unsigned short* __restrict__ WTl,
    const unsigned short* __restrict__ WTr,
    const float* __restrict__ bias,
    unsigned short* __restrict__ Pl,
    unsigned short* __restrict__ Qr, int M) {
    const int wave = tid >> 6;
    const int lane = tid & 63;
    const int m0 = bid * (WPB * 16) + wave * 16;
    const int lr = lane & 15;
    const int lk = lane >> 4;

    int arow = m0 + lr;
    if (arow >= M) arow = M - 1;

    bf16x8 af[4];
    if (A_F32) {
        const float* Ab = (const float*)Av + (size_t)arow * 128 + lk * 8;
#pragma unroll
        for (int s = 0; s < 4; ++s) {
            float4 v0 = *(const float4*)(Ab + s * 32);
            float4 v1 = *(const float4*)(Ab + s * 32 + 4);
            unsigned short t[8] = {f2bf(v0.x), f2bf(v0.y), f2bf(v0.z), f2bf(v0.w),
                                   f2bf(v1.x), f2bf(v1.y), f2bf(v1.z), f2bf(v1.w)};
            af[s] = *(const bf16x8*)t;
        }
    } else {
        const unsigned short* Ab = (const unsigned short*)Av + (size_t)arow * 128 + lk * 8;
#pragma unroll
        for (int s = 0; s < 4; ++s) af[s] = *(const bf16x8*)(Ab + s * 32);
    }

#pragma unroll
    for (int ct = 0; ct < NC / 16; ++ct) {
        const unsigned short* Bl = WTl + (size_t)(ct * 16 + lr) * 128 + lk * 8;
        const unsigned short* Br = WTr + (size_t)(ct * 16 + lr) * 128 + lk * 8;
        f32x4 accL = {0.f, 0.f, 0.f, 0.f};
        f32x4 accR = {0.f, 0.f, 0.f, 0.f};
#pragma unroll
        for (int s = 0; s < 4; ++s) {
            bf16x8 bl = *(const bf16x8*)(Bl + s * 32);
            bf16x8 br = *(const bf16x8*)(Br + s * 32);
            accL = __builtin_amdgcn_mfma_f32_16x16x32_bf16(af[s], bl, accL, 0, 0, 0);
            accR = __builtin_amdgcn_mfma_f32_16x16x32_bf16(af[s], br, accR, 0, 0, 0);
        }
        float bcol = bias[ct * 16 + lr];
#pragma unroll
        for (int r = 0; r < 4; ++r) {
            int gr = m0 + lk * 4 + r;
            if (gr < M) {
                Pl[(size_t)gr * NC + ct * 16 + lr] = f2bf(accL[r]);
                Qr[(size_t)gr * NC + ct * 16 + lr] = f2bf(accR[r] + bcol);
            }
        }
    }
}

// ---------------- D1: hist + packed-edge emit + weight prep ----------------
// 512 threads; 2x-unrolled edge loop. Range-0 blocks also write
// packed[e] = (src<<16)|dst (both < 65536).

__global__ __launch_bounds__(512) void hist_wt_kernel(
    const int* __restrict__ src, const int* __restrict__ dst,
    int* __restrict__ hist, unsigned* __restrict__ packed, int E, int N,
    const float* __restrict__ W1l, const float* __restrict__ W1r,
    const float* __restrict__ W2l, const float* __restrict__ W2r,
    unsigned short* __restrict__ T1l, unsigned short* __restrict__ T1r,
    unsigned short* __restrict__ T2l, unsigned short* __restrict__ T2r) {
    __shared__ int lhist[PACKED_W];
    const int tid = threadIdx.x;
    if ((int)blockIdx.x >= NHIST) {
        int i = (blockIdx.x - NHIST) * 512 + tid;
        if (i < 16384) {
            int k = i >> 7, n = i & 127;
            T1l[n * 128 + k] = f2bf(W1l[i]);
            T1r[n * 128 + k] = f2bf(W1r[i]);
        } else if (i < 16384 + 8192) {
            int m = i - 16384;
            int k = m >> 6, n = m & 63;
            T2l[n * 128 + k] = f2bf(W2l[m]);
            T2r[n * 128 + k] = f2bf(W2r[m]);
        }
        return;
    }
    const int b = blockIdx.x;
    const int r = b & (NRANGE - 1);
    const int j = b >> 3;
    const int lo = r * RANGE_W;
    const int w = min(N - lo, RANGE_W);
    for (int i = tid; i < PACKED_W; i += 512) lhist[i] = 0;
    __syncthreads();
    const int stripe = stripe_len(E);
    const int s0 = j * stripe;
    const int s1 = min(E, s0 + stripe);
    for (int e = s0 + tid * 4; e < s1; e += 4096) {
        int4 dA = *(const int4*)(dst + e);
        int eB = e + 2048;
        bool hb = eB < s1;
        int4 dB = hb ? *(const int4*)(dst + eB) : dA;
        if (r == 0) {
            int4 sA = *(const int4*)(src + e);
            uint4 pA;
            pA.x = ((unsigned)sA.x << 16) | (unsigned)dA.x;
            pA.y = ((unsigned)sA.y << 16) | (unsigned)dA.y;
            pA.z = ((unsigned)sA.z << 16) | (unsigned)dA.z;
            pA.w = ((unsigned)sA.w << 16) | (unsigned)dA.w;
            *(uint4*)(packed + e) = pA;
            if (hb) {
                int4 sB = *(const int4*)(src + eB);
                uint4 pB;
                pB.x = ((unsigned)sB.x << 16) | (unsigned)dB.x;
                pB.y = ((unsigned)sB.y << 16) | (unsigned)dB.y;
                pB.z = ((unsigned)sB.z << 16) | (unsigned)dB.z;
                pB.w = ((unsigned)sB.w << 16) | (unsigned)dB.w;
                *(uint4*)(packed + eB) = pB;
            }
        }
        int a0 = dA.x - lo, a1 = dA.y - lo, a2 = dA.z - lo, a3 = dA.w - lo;
        if ((unsigned)a0 < (unsigned)w) atomicAdd(&lhist[a0 >> 1], 1u << ((a0 & 1) * 16));
        if ((unsigned)a1 < (unsigned)w) atomicAdd(&lhist[a1 >> 1], 1u << ((a1 & 1) * 16));
        if ((unsigned)a2 < (unsigned)w) atomicAdd(&lhist[a2 >> 1], 1u << ((a2 & 1) * 16));
        if ((unsigned)a3 < (unsigned)w) atomicAdd(&lhist[a3 >> 1], 1u << ((a3 & 1) * 16));
        if (hb) {
            int b0 = dB.x - lo, b1_ = dB.y - lo, b2_ = dB.z - lo, b3 = dB.w - lo;
            if ((unsigned)b0 < (unsigned)w) atomicAdd(&lhist[b0 >> 1], 1u << ((b0 & 1) * 16));
            if ((unsigned)b1_ < (unsigned)w) atomicAdd(&lhist[b1_ >> 1], 1u << ((b1_ & 1) * 16));
            if ((unsigned)b2_ < (unsigned)w) atomicAdd(&lhist[b2_ >> 1], 1u << ((b2_ & 1) * 16));
            if ((unsigned)b3 < (unsigned)w) atomicAdd(&lhist[b3 >> 1], 1u << ((b3 & 1) * 16));
        }
    }
    __syncthreads();
    int* gh = hist + ((size_t)r * NSTRIPE + j) * PACKED_W;
    for (int i = tid; i < PACKED_W; i += 512) gh[i] = lhist[i];
}

// ---------------- D2: scan ----------------

__global__ __launch_bounds__(256) void scan16_kernel(const int* __restrict__ hist,
                                                     int* __restrict__ row_start,
                                                     int* __restrict__ bsum, int N) {
    __shared__ int lds[256];
    int i = blockIdx.x * 256 + threadIdx.x;
    int v = 0;
    if (i < N) {
        int r = i / RANGE_W, loc = i - r * RANGE_W;
        const int* hp = hist + (size_t)r * NSTRIPE * PACKED_W + (loc >> 1);
        int sh = (loc & 1) * 16;
#pragma unroll 8
        for (int j = 0; j < NSTRIPE; ++j) v += (hp[j * PACKED_W] >> sh) & 0xffff;
    }
    lds[threadIdx.x] = v;
    __syncthreads();
    for (int off = 1; off < 256; off <<= 1) {
        int t = (threadIdx.x >= off) ? lds[threadIdx.x - off] : 0;
        __syncthreads();
        lds[threadIdx.x] += t;
        __syncthreads();
    }
    if (i < N) row_start[i] = lds[threadIdx.x] - v;
    if (threadIdx.x == 255) bsum[blockIdx.x] = lds[255];
}

// ---------------- D3: global prefix + absolute cursors ----------------

__global__ __launch_bounds__(256) void add_off_base_kernel(int* __restrict__ row_start,
                                                           const int* __restrict__ bsum,
                                                           const int* __restrict__ hist,
                                                           int* __restrict__ cur,
                                                           int N, int E) {
    __shared__ int lds[256];
    int b = blockIdx.x;
    lds[threadIdx.x] = (threadIdx.x < b) ? bsum[threadIdx.x] : 0;
    __syncthreads();
    for (int off = 128; off > 0; off >>= 1) {
        if (threadIdx.x < off) lds[threadIdx.x] += lds[threadIdx.x + off];
        __syncthreads();
    }
    int prefix = lds[0];
    int i = b * 256 + threadIdx.x;
    if (i < N) {
        int s = row_start[i] + prefix;
        row_start[i] = s;
        int r = i / RANGE_W, loc = i - r * RANGE_W;
        const int* hp = hist + (size_t)r * NSTRIPE * PACKED_W + (loc >> 1);
        int* cp = cur + (size_t)r * NSTRIPE * RANGE_W + loc;
        int sh = (loc & 1) * 16;
#pragma unroll 8
        for (int j = 0; j < NSTRIPE; ++j) {
            int h = (hp[j * PACKED_W] >> sh) & 0xffff;
            cp[j * RANGE_W] = s;
            s += h;
        }
    }
    if (b == 0 && threadIdx.x == 0) row_start[N] = E;
}

// ---------------- D4: scatter (packed edges) + GEMM-1 (backfill) ----------

__global__ __launch_bounds__(512) void scatter_gemm1_kernel(
    const unsigned* __restrict__ packed,
    const int* __restrict__ cur, int* __restrict__ csr_src, int E, int N,
    const float* __restrict__ x,
    const unsigned short* __restrict__ wt1l,
    const unsigned short* __restrict__ wt1r,
    const float* __restrict__ b1,
    unsigned short* __restrict__ Pl,
    unsigned short* __restrict__ Qr, int M) {
    __shared__ __align__(16) int lcur[RANGE_W];
    const int tid = threadIdx.x;
    if ((int)blockIdx.x >= NHIST) {
        gemm_body<128, true, 8>(blockIdx.x - NHIST, tid, x, wt1l, wt1r, b1, Pl, Qr, M);
        return;
    }
    const int b = blockIdx.x;
    const int r = b & (NRANGE - 1);
    const int j = b >> 3;
    const int lo = r * RANGE_W;
    const int w = min(N - lo, RANGE_W);
    const int* gb = cur + ((size_t)r * NSTRIPE + j) * RANGE_W;
    {
        int w4 = w & ~3;
        for (int i = tid * 4; i < w4; i += 2048)
            *(int4*)(&lcur[i]) = *(const int4*)(gb + i);
        for (int i = w4 + tid; i < w; i += 512) lcur[i] = gb[i];
    }
    __syncthreads();
    const int stripe = stripe_len(E);
    const int s0 = j * stripe;
    const int s1 = min(E, s0 + stripe);
    for (int e = s0 + tid * 4; e < s1; e += 4096) {
        uint4 pA = *(const uint4*)(packed + e);
        int eB = e + 2048;
        bool hb = eB < s1;
        uint4 pB = hb ? *(const uint4*)(packed + eB) : pA;
        int a0 = (int)(pA.x & 0xffffu) - lo, a1 = (int)(pA.y & 0xffffu) - lo;
        int a2 = (int)(pA.z & 0xffffu) - lo, a3 = (int)(pA.w & 0xffffu) - lo;
        if ((unsigned)a0 < (unsigned)w) { int p = atomicAdd(&lcur[a0], 1); csr_src[p] = (int)(pA.x >> 16); }
        if ((unsigned)a1 < (unsigned)w) { int p = atomicAdd(&lcur[a1], 1); csr_src[p] = (int)(pA.y >> 16); }
        if ((unsigned)a2 < (unsigned)w) { int p = atomicAdd(&lcur[a2], 1); csr_src[p] = (int)(pA.z >> 16); }
        if ((unsigned)a3 < (unsigned)w) { int p = atomicAdd(&lcur[a3], 1); csr_src[p] = (int)(pA.w >> 16); }
        if (hb) {
            int b0 = (int)(pB.x & 0xffffu) - lo, b1_ = (int)(pB.y & 0xffffu) - lo;
            int b2_ = (int)(pB.z & 0xffffu) - lo, b3 = (int)(pB.w & 0xffffu) - lo;
            if ((unsigned)b0 < (unsigned)w) { int p = atomicAdd(&lcur[b0], 1); csr_src[p] = (int)(pB.x >> 16); }
            if ((unsigned)b1_ < (unsigned)w) { int p = atomicAdd(&lcur[b1_], 1); csr_src[p] = (int)(pB.y >> 16); }
            if ((unsigned)b2_ < (unsigned)w) { int p = atomicAdd(&lcur[b2_], 1); csr_src[p] = (int)(pB.z >> 16); }
            if ((unsigned)b3 < (unsigned)w) { int p = atomicAdd(&lcur[b3], 1); csr_src[p] = (int)(pB.w >> 16); }
        }
    }
}

__global__ __launch_bounds__(256) void mfma_dual_gemm2(
    const unsigned short* __restrict__ A,
    const unsigned short* __restrict__ WTl,
    const unsigned short* __restrict__ WTr,
    const float* __restrict__ b2,
    unsigned short* __restrict__ Pl,
    unsigned short* __restrict__ Qr, int M) {
    gemm_body<64, false, 4>(blockIdx.x, threadIdx.x, A, WTl, WTr, b2, Pl, Qr, M);
}

// ---------------- aggregation ----------------
// layer 1: h[n] = relu( mean(p[src]) + q[n] ); p,q,h bf16; 128 ch.
// 16 nodes/block; 4 nodes/wave, 16 lanes/node, 8 ch (16B) per lane; 8-deep.
__global__ __launch_bounds__(256) void agg1_kernel(const unsigned short* __restrict__ p,
                                                   const unsigned short* __restrict__ q,
                                                   const int* __restrict__ row_start,
                                                   const int* __restrict__ csr_src,
                                                   unsigned short* __restrict__ h, int N) {
    int tid = threadIdx.x;
    int n = blockIdx.x * 16 + (tid >> 4);
    int lane = tid & 15;
    if (n >= N) return;
    int s0 = row_start[n], s1 = row_start[n + 1];
    float acc[8] = {};
    const unsigned short* pc = p + lane * 8;
    int e = s0;
    for (; e + 7 < s1; e += 8) {
        uint4 v0 = *(const uint4*)(pc + (size_t)csr_src[e]     * 128);
        uint4 v1 = *(const uint4*)(pc + (size_t)csr_src[e + 1] * 128);
        uint4 v2 = *(const uint4*)(pc + (size_t)csr_src[e + 2] * 128);
        uint4 v3 = *(const uint4*)(pc + (size_t)csr_src[e + 3] * 128);
        uint4 v4 = *(const uint4*)(pc + (size_t)csr_src[e + 4] * 128);
        uint4 v5 = *(const uint4*)(pc + (size_t)csr_src[e + 5] * 128);
        uint4 v6 = *(const uint4*)(pc + (size_t)csr_src[e + 6] * 128);
        uint4 v7 = *(const uint4*)(pc + (size_t)csr_src[e + 7] * 128);
        acc[0] += ((bf_lo(v0.x) + bf_lo(v1.x)) + (bf_lo(v2.x) + bf_lo(v3.x)))
                + ((bf_lo(v4.x) + bf_lo(v5.x)) + (bf_lo(v6.x) + bf_lo(v7.x)));
        acc[1] += ((bf_hi(v0.x) + bf_hi(v1.x)) + (bf_hi(v2.x) + bf_hi(v3.x)))
                + ((bf_hi(v4.x) + bf_hi(v5.x)) + (bf_hi(v6.x) + bf_hi(v7.x)));
        acc[2] += ((bf_lo(v0.y) + bf_lo(v1.y)) + (bf_lo(v2.y) + bf_lo(v3.y)))
                + ((bf_lo(v4.y) + bf_lo(v5.y)) + (bf_lo(v6.y) + bf_lo(v7.y)));
        acc[3] += ((bf_hi(v0.y) + bf_hi(v1.y)) + (bf_hi(v2.y) + bf_hi(v3.y)))
                + ((bf_hi(v4.y) + bf_hi(v5.y)) + (bf_hi(v6.y) + bf_hi(v7.y)));
        acc[4] += ((bf_lo(v0.z) + bf_lo(v1.z)) + (bf_lo(v2.z) + bf_lo(v3.z)))
                + ((bf_lo(v4.z) + bf_lo(v5.z)) + (bf_lo(v6.z) + bf_lo(v7.z)));
        acc[5] += ((bf_hi(v0.z) + bf_hi(v1.z)) + (bf_hi(v2.z) + bf_hi(v3.z)))
                + ((bf_hi(v4.z) + bf_hi(v5.z)) + (bf_hi(v6.z) + bf_hi(v7.z)));
        acc[6] += ((bf_lo(v0.w) + bf_lo(v1.w)) + (bf_lo(v2.w) + bf_lo(v3.w)))
                + ((bf_lo(v4.w) + bf_lo(v5.w)) + (bf_lo(v6.w) + bf_lo(v7.w)));
        acc[7] += ((bf_hi(v0.w) + bf_hi(v1.w)) + (bf_hi(v2.w) + bf_hi(v3.w)))
                + ((bf_hi(v4.w) + bf_hi(v5.w)) + (bf_hi(v6.w) + bf_hi(v7.w)));
    }
    for (; e + 3 < s1; e += 4) {
        uint4 v0 = *(const uint4*)(pc + (size_t)csr_src[e]     * 128);
        uint4 v1 = *(const uint4*)(pc + (size_t)csr_src[e + 1] * 128);
        uint4 v2 = *(const uint4*)(pc + (size_t)csr_src[e + 2] * 128);
        uint4 v3 = *(const uint4*)(pc + (size_t)csr_src[e + 3] * 128);
        acc[0] += (bf_lo(v0.x) + bf_lo(v1.x)) + (bf_lo(v2.x) + bf_lo(v3.x));
        acc[1] += (bf_hi(v0.x) + bf_hi(v1.x)) + (bf_hi(v2.x) + bf_hi(v3.x));
        acc[2] += (bf_lo(v0.y) + bf_lo(v1.y)) + (bf_lo(v2.y) + bf_lo(v3.y));
        acc[3] += (bf_hi(v0.y) + bf_hi(v1.y)) + (bf_hi(v2.y) + bf_hi(v3.y));
        acc[4] += (bf_lo(v0.z) + bf_lo(v1.z)) + (bf_lo(v2.z) + bf_lo(v3.z));
        acc[5] += (bf_hi(v0.z) + bf_hi(v1.z)) + (bf_hi(v2.z) + bf_hi(v3.z));
        acc[6] += (bf_lo(v0.w) + bf_lo(v1.w)) + (bf_lo(v2.w) + bf_lo(v3.w));
        acc[7] += (bf_hi(v0.w) + bf_hi(v1.w)) + (bf_hi(v2.w) + bf_hi(v3.w));
    }
    for (; e < s1; ++e) {
        uint4 v0 = *(const uint4*)(pc + (size_t)csr_src[e] * 128);
        acc[0] += bf_lo(v0.x); acc[1] += bf_hi(v0.x);
        acc[2] += bf_lo(v0.y); acc[3] += bf_hi(v0.y);
        acc[4] += bf_lo(v0.z); acc[5] += bf_hi(v0.z);
        acc[6] += bf_lo(v0.w); acc[7] += bf_hi(v0.w);
    }
    float inv = 1.0f / (float)max(s1 - s0, 1);
    uint4 qv = *(const uint4*)(q + (size_t)n * 128 + lane * 8);
    float hv[8];
    hv[0] = fmaxf(fmaf(acc[0], inv, bf_lo(qv.x)), 0.f);
    hv[1] = fmaxf(fmaf(acc[1], inv, bf_hi(qv.x)), 0.f);
    hv[2] = fmaxf(fmaf(acc[2], inv, bf_lo(qv.y)), 0.f);
    hv[3] = fmaxf(fmaf(acc[3], inv, bf_hi(qv.y)), 0.f);
    hv[4] = fmaxf(fmaf(acc[4], inv, bf_lo(qv.z)), 0.f);
    hv[5] = fmaxf(fmaf(acc[5], inv, bf_hi(qv.z)), 0.f);
    hv[6] = fmaxf(fmaf(acc[6], inv, bf_lo(qv.w)), 0.f);
    hv[7] = fmaxf(fmaf(acc[7], inv, bf_hi(qv.w)), 0.f);
    uint4 o;
    o.x = packbf(hv[0], hv[1]); o.y = packbf(hv[2], hv[3]);
    o.z = packbf(hv[4], hv[5]); o.w = packbf(hv[6], hv[7]);
    *(uint4*)(h + (size_t)n * 128 + lane * 8) = o;
}

// layer 2: out[n] = mean(g[src]) + r[n]; g,r bf16; out f32; 64 ch; 8-deep.
__global__ __launch_bounds__(256) void agg2_kernel(const unsigned short* __restrict__ g,
                                                   const unsigned short* __restrict__ r,
                                                   const int* __restrict__ row_start,
                                                   const int* __restrict__ csr_src,
                                                   float* __restrict__ out, int N) {
    int tid = threadIdx.x;
    int n = blockIdx.x * 16 + (tid >> 4);
    int lane = tid & 15;
    if (n >= N) return;
    int s0 = row_start[n], s1 = row_start[n + 1];
    float acc[4] = {};
    const unsigned short* gc = g + lane * 4;
    int e = s0;
    for (; e + 7 < s1; e += 8) {
        uint2 v0 = *(const uint2*)(gc + (size_t)csr_src[e]     * 64);
        uint2 v1 = *(const uint2*)(gc + (size_t)csr_src[e + 1] * 64);
        uint2 v2 = *(const uint2*)(gc + (size_t)csr_src[e + 2] * 64);
        uint2 v3 = *(const uint2*)(gc + (size_t)csr_src[e + 3] * 64);
        uint2 v4 = *(const uint2*)(gc + (size_t)csr_src[e + 4] * 64);
        uint2 v5 = *(const uint2*)(gc + (size_t)csr_src[e + 5] * 64);
        uint2 v6 = *(const uint2*)(gc + (size_t)csr_src[e + 6] * 64);
        uint2 v7 = *(const uint2*)(gc + (size_t)csr_src[e + 7] * 64);
        acc[0] += ((bf_lo(v0.x) + bf_lo(v1.x)) + (bf_lo(v2.x) + bf_lo(v3.x)))
                + ((bf_lo(v4.x) + bf_lo(v5.x)) + (bf_lo(v6.x) + bf_lo(v7.x)));
        acc[1] += ((bf_hi(v0.x) + bf_hi(v1.x)) + (bf_hi(v2.x) + bf_hi(v3.x)))
                + ((bf_hi(v4.x) + bf_hi(v5.x)) + (bf_hi(v6.x) + bf_hi(v7.x)));
        acc[2] += ((bf_lo(v0.y) + bf_lo(v1.y)) + (bf_lo(v2.y) + bf_lo(v3.y)))
                + ((bf_lo(v4.y) + bf_lo(v5.y)) + (bf_lo(v6.y) + bf_lo(v7.y)));
        acc[3] += ((bf_hi(v0.y) + bf_hi(v1.y)) + (bf_hi(v2.y) + bf_hi(v3.y)))
                + ((bf_hi(v4.y) + bf_hi(v5.y)) + (bf_hi(v6.y) + bf_hi(v7.y)));
    }
    for (; e + 3 < s1; e += 4) {
        uint2 v0 = *(const uint2*)(gc + (size_t)csr_src[e]     * 64);
        uint2 v1 = *(const uint2*)(gc + (size_t)csr_src[e + 1] * 64);
        uint2 v2 = *(const uint2*)(gc + (size_t)csr_src[e + 2] * 64);
        uint2 v3 = *(const uint2*)(gc + (size_t)csr_src[e + 3] * 64);
        acc[0] += (bf_lo(v0.x) + bf_lo(v1.x)) + (bf_lo(v2.x) + bf_lo(v3.x));
        acc[1] += (bf_hi(v0.x) + bf_hi(v1.x)) + (bf_hi(v2.x) + bf_hi(v3.x));
        acc[2] += (bf_lo(v0.y) + bf_lo(v1.y)) + (bf_lo(v2.y) + bf_lo(v3.y));
        acc[3] += (bf_hi(v0.y) + bf_hi(v1.y)) + (bf_hi(v2.y) + bf_hi(v3.y));
    }
    for (; e < s1; ++e) {
        uint2 v0 = *(const uint2*)(gc + (size_t)csr_src[e] * 64);
        acc[0] += bf_lo(v0.x); acc[1] += bf_hi(v0.x);
        acc[2] += bf_lo(v0.y); acc[3] += bf_hi(v0.y);
    }
    float inv = 1.0f / (float)max(s1 - s0, 1);
    uint2 rv = *(const uint2*)(r + (size_t)n * 64 + lane * 4);
    float4 o;
    o.x = fmaf(acc[0], inv, bf_lo(rv.x));
    o.y = fmaf(acc[1], inv, bf_hi(rv.x));
    o.z = fmaf(acc[2], inv, bf_lo(rv.y));
    o.w = fmaf(acc[3], inv, bf_hi(rv.y));
    *(float4*)(out + (size_t)n * 64 + lane * 4) = o;
}

// ---------------------------------------------------------------------------

extern "C" void kernel_launch(void* const* d_in, const int* in_sizes, int n_in,
                              void* d_out, int out_size, void* d_ws, size_t ws_size,
                              hipStream_t stream) {
    const float* x    = (const float*)d_in[0];
    const int*   ei   = (const int*)d_in[1];
    const float* W1_l = (const float*)d_in[2];
    const float* b1   = (const float*)d_in[3];
    const float* W1_r = (const float*)d_in[4];
    const float* W2_l = (const float*)d_in[5];
    const float* b2   = (const float*)d_in[6];
    const float* W2_r = (const float*)d_in[7];

    const int N = in_sizes[0] / 128;   // 50000
    const int E = in_sizes[1] / 2;     // 800000
    const int* e_src = ei;
    const int* e_dst = ei + E;

    // ---- workspace layout ----
    char* ws = (char*)d_ws;
    auto align256 = [](size_t v) { return (v + 255) & ~(size_t)255; };
    size_t off = 0;
    int* row_start = (int*)(ws + off); off += align256((size_t)(N + 1) * 4);
    int* bsum      = (int*)(ws + off); off += align256(1024);
    int* hist      = (int*)(ws + off); off += align256((size_t)NRANGE * NSTRIPE * PACKED_W * 4);
    int* cur       = (int*)(ws + off); off += align256((size_t)NRANGE * NSTRIPE * RANGE_W * 4);
    unsigned* packed = (unsigned*)(ws + off); off += align256((size_t)E * 4);
    int* csr_src   = (int*)(ws + off); off += align256((size_t)E * 4);
    unsigned short* h_bf  = (unsigned short*)(ws + off); off += align256((size_t)N * 128 * 2);
    unsigned short* pg_bf = (unsigned short*)(ws + off); off += align256((size_t)N * 128 * 2);
    unsigned short* qr_bf = (unsigned short*)(ws + off); off += align256((size_t)N * 128 * 2);
    unsigned short* wt1l  = (unsigned short*)(ws + off); off += align256(128 * 128 * 2);
    unsigned short* wt1r  = (unsigned short*)(ws + off); off += align256(128 * 128 * 2);
    unsigned short* wt2l  = (unsigned short*)(ws + off); off += align256(128 * 64 * 2);
    unsigned short* wt2r  = (unsigned short*)(ws + off); off += align256(128 * 64 * 2);
    float* out = (float*)d_out;

    const int nb = (N + 255) / 256;
    const int nGemm1Wg = (N + 127) / 128;                 // 391 (128 rows/block)
    const int nWtWg = (16384 + 8192 + 511) / 512;         // 48

    // ---- D1: histogram + packed edges + weight prep (hist first, 512 thr) --
    hist_wt_kernel<<<NHIST + nWtWg, 512, 0, stream>>>(
        e_src, e_dst, hist, packed, E, N,
        W1_l, W1_r, W2_l, W2_r, wt1l, wt1r, wt2l, wt2r);
    // ---- D2/D3: CSR scan (no global atomics) ----
    scan16_kernel<<<nb, 256, 0, stream>>>(hist, row_start, bsum, N);
    add_off_base_kernel<<<nb, 256, 0, stream>>>(row_start, bsum, hist, cur, N, E);
    // ---- D4: scatter (packed) + GEMM-1 (p, q+b1) fused, scatter first ----
    scatter_gemm1_kernel<<<NHIST + nGemm1Wg, 512, 0, stream>>>(
        packed, cur, csr_src, E, N,
        x, wt1l, wt1r, b1, pg_bf, qr_bf, N);
    // ---- layer 1 aggregate ----
    agg1_kernel<<<(N + 15) / 16, 256, 0, stream>>>(pg_bf, qr_bf, row_start,
                                                   csr_src, h_bf, N);
    // ---- layer 2 ----
    mfma_dual_gemm2<<<(N + 63) / 64, 256, 0, stream>>>(h_bf, wt2l, wt2r, b2,
                                                       pg_bf, qr_bf, N);
    agg2_kernel<<<(N + 15) / 16, 256, 0, stream>>>(pg_bf, qr_bf, row_start,
                                                   csr_src, out, N);
}

// Round 14
// 135.023 us; speedup vs baseline: 1.0606x; 1.0606x over previous
//
#include <hip/hip_runtime.h>
#include <hip/hip_bf16.h>

// ---------------------------------------------------------------------------
// GraphSAGE 2-layer forward.
//   h   = relu( mean_agg(x) @ W1_l + b1 + x @ W1_r )
//   out =       mean_agg(h) @ W2_l + b2 + h @ W2_r
// agg(x)@W == agg(x@W): transform-then-aggregate. Biases folded into GEMM
// epilogues (q = x@W1_r + b1, r = h@W2_r + b2).
// bf16 MFMA GEMMs; bf16 gather buffers (p,g) and addends (q,r); fp32 out.
// CSR build with ZERO global atomics; NRANGE=4 (halves the counting sort's
// redundant edge-stream reads vs 8):
//   D1 hist+wt (512 thr): packed 2xushort LDS hist (25 KB); range-0 blocks
//      emit packed edges (src16|dst16); weight-transpose blocks backfill.
//   D2 scan16: cnt[n] = sum_j hist, block scan -> row_start.
//   D3 add_off_base: global prefix; absolute cursors (unpacked) to cur.
//   D4 scatter+GEMM1 (512 thr): scatter blocks first (50 KB LDS cursors,
//      LDS-atomic pos, plain stores); GEMM-1 blocks (128 rows) backfill.
//   D5 agg1 + FUSED GEMM-2: gather/mean/relu 16 h-rows into LDS, then the
//      block's 4 waves MFMA h@W2_{l,r} -> g, r directly (no h round-trip).
//   D6 agg2: out = mean(g[src]) + r.
// ---------------------------------------------------------------------------

typedef __attribute__((ext_vector_type(8))) short bf16x8;
typedef __attribute__((ext_vector_type(4))) float f32x4;

static __device__ __forceinline__ float bf_lo(unsigned u) {
    u <<= 16; return __builtin_bit_cast(float, u);
}
static __device__ __forceinline__ float bf_hi(unsigned u) {
    u &= 0xffff0000u; return __builtin_bit_cast(float, u);
}
static __device__ __forceinline__ unsigned short f2bf(float f) {
    __hip_bfloat16 b = __float2bfloat16(f);
    return __builtin_bit_cast(unsigned short, b);
}
static __device__ __forceinline__ unsigned packbf(float lo, float hi) {
    return (unsigned)f2bf(lo) | ((unsigned)f2bf(hi) << 16);
}

#define NRANGE   4
#define RANGE_W  12500     // N == 4*12500 exactly
#define PACKED_W 6250      // RANGE_W/2, two ushort counts per int
#define NSTRIPE  32
#define NHIST    (NRANGE * NSTRIPE)   // 128

static __device__ __forceinline__ int stripe_len(int E) {
    return ((E / NSTRIPE) + 3) & ~3;  // multiple of 4 for int4 alignment
}

// ---------------- MFMA dual GEMM body ----------------
// A[M][128] row-major (fp32 if A_F32 else bf16); WTl/WTr[NC][128] bf16 (=W^T).
// Pl = A@Wl (bf16), Qr = A@Wr + bias (bf16). One wave = 16 output rows;
// WPB waves per block. mfma_f32_16x16x32_bf16: A lane l -> row l&15,
// k=(l>>4)*8+j; B lane l -> col l&15, same k; D: col=lane&15, row=(lane>>4)*4+reg.

template <int NC, bool A_F32, int WPB>
static __device__ __forceinline__ void gemm_body(
    int bid, int tid, const void* __restrict__ Av,
    const unsigned short* __restrict__ WTl,
    const unsigned short* __restrict__ WTr,
    const float* __restrict__ bias,
    unsigned short* __restrict__ Pl,
    unsigned short* __restrict__ Qr, int M) {
    const int wave = tid >> 6;
    const int lane = tid & 63;
    const int m0 = bid * (WPB * 16) + wave * 16;
    const int lr = lane & 15;
    const int lk = lane >> 4;

    int arow = m0 + lr;
    if (arow >= M) arow = M - 1;

    bf16x8 af[4];
    if (A_F32) {
        const float* Ab = (const float*)Av + (size_t)arow * 128 + lk * 8;
#pragma unroll
        for (int s = 0; s < 4; ++s) {
            float4 v0 = *(const float4*)(Ab + s * 32);
            float4 v1 = *(const float4*)(Ab + s * 32 + 4);
            unsigned short t[8] = {f2bf(v0.x), f2bf(v0.y), f2bf(v0.z), f2bf(v0.w),
                                   f2bf(v1.x), f2bf(v1.y), f2bf(v1.z), f2bf(v1.w)};
            af[s] = *(const bf16x8*)t;
        }
    } else {
        const unsigned short* Ab = (const unsigned short*)Av + (size_t)arow * 128 + lk * 8;
#pragma unroll
        for (int s = 0; s < 4; ++s) af[s] = *(const bf16x8*)(Ab + s * 32);
    }

#pragma unroll
    for (int ct = 0; ct < NC / 16; ++ct) {
        const unsigned short* Bl = WTl + (size_t)(ct * 16 + lr) * 128 + lk * 8;
        const unsigned short* Br = WTr + (size_t)(ct * 16 + lr) * 128 + lk * 8;
        f32x4 accL = {0.f, 0.f, 0.f, 0.f};
        f32x4 accR = {0.f, 0.f, 0.f, 0.f};
#pragma unroll
        for (int s = 0; s < 4; ++s) {
            bf16x8 bl = *(const bf16x8*)(Bl + s * 32);
            bf16x8 br = *(const bf16x8*)(Br + s * 32);
            accL = __builtin_amdgcn_mfma_f32_16x16x32_bf16(af[s], bl, accL, 0, 0, 0);
            accR = __builtin_amdgcn_mfma_f32_16x16x32_bf16(af[s], br, accR, 0, 0, 0);
        }
        float bcol = bias[ct * 16 + lr];
#pragma unroll
        for (int r = 0; r < 4; ++r) {
            int gr = m0 + lk * 4 + r;
            if (gr < M) {
                Pl[(size_t)gr * NC + ct * 16 + lr] = f2bf(accL[r]);
                Qr[(size_t)gr * NC + ct * 16 + lr] = f2bf(accR[r] + bcol);
            }
        }
    }
}

// ---------------- D1: hist + packed-edge emit + weight prep ----------------

__global__ __launch_bounds__(512) void hist_wt_kernel(
    const int* __restrict__ src, const int* __restrict__ dst,
    int* __restrict__ hist, unsigned* __restrict__ packed, int E, int N,
    const float* __restrict__ W1l, const float* __restrict__ W1r,
    const float* __restrict__ W2l, const float* __restrict__ W2r,
    unsigned short* __restrict__ T1l, unsigned short* __restrict__ T1r,
    unsigned short* __restrict__ T2l, unsigned short* __restrict__ T2r) {
    __shared__ int lhist[PACKED_W];
    const int tid = threadIdx.x;
    if ((int)blockIdx.x >= NHIST) {
        int i = (blockIdx.x - NHIST) * 512 + tid;
        if (i < 16384) {
            int k = i >> 7, n = i & 127;
            T1l[n * 128 + k] = f2bf(W1l[i]);
            T1r[n * 128 + k] = f2bf(W1r[i]);
        } else if (i < 16384 + 8192) {
            int m = i - 16384;
            int k = m >> 6, n = m & 63;
            T2l[n * 128 + k] = f2bf(W2l[m]);
            T2r[n * 128 + k] = f2bf(W2r[m]);
        }
        return;
    }
    const int b = blockIdx.x;
    const int r = b & (NRANGE - 1);
    const int j = b / NRANGE;
    const int lo = r * RANGE_W;
    const int w = min(N - lo, RANGE_W);
    for (int i = tid; i < PACKED_W; i += 512) lhist[i] = 0;
    __syncthreads();
    const int stripe = stripe_len(E);
    const int s0 = j * stripe;
    const int s1 = min(E, s0 + stripe);
    for (int e = s0 + tid * 4; e < s1; e += 4096) {
        int4 dA = *(const int4*)(dst + e);
        int eB = e + 2048;
        bool hb = eB < s1;
        int4 dB = hb ? *(const int4*)(dst + eB) : dA;
        if (r == 0) {
            int4 sA = *(const int4*)(src + e);
            uint4 pA;
            pA.x = ((unsigned)sA.x << 16) | (unsigned)dA.x;
            pA.y = ((unsigned)sA.y << 16) | (unsigned)dA.y;
            pA.z = ((unsigned)sA.z << 16) | (unsigned)dA.z;
            pA.w = ((unsigned)sA.w << 16) | (unsigned)dA.w;
            *(uint4*)(packed + e) = pA;
            if (hb) {
                int4 sB = *(const int4*)(src + eB);
                uint4 pB;
                pB.x = ((unsigned)sB.x << 16) | (unsigned)dB.x;
                pB.y = ((unsigned)sB.y << 16) | (unsigned)dB.y;
                pB.z = ((unsigned)sB.z << 16) | (unsigned)dB.z;
                pB.w = ((unsigned)sB.w << 16) | (unsigned)dB.w;
                *(uint4*)(packed + eB) = pB;
            }
        }
        int a0 = dA.x - lo, a1 = dA.y - lo, a2 = dA.z - lo, a3 = dA.w - lo;
        if ((unsigned)a0 < (unsigned)w) atomicAdd(&lhist[a0 >> 1], 1u << ((a0 & 1) * 16));
        if ((unsigned)a1 < (unsigned)w) atomicAdd(&lhist[a1 >> 1], 1u << ((a1 & 1) * 16));
        if ((unsigned)a2 < (unsigned)w) atomicAdd(&lhist[a2 >> 1], 1u << ((a2 & 1) * 16));
        if ((unsigned)a3 < (unsigned)w) atomicAdd(&lhist[a3 >> 1], 1u << ((a3 & 1) * 16));
        if (hb) {
            int b0 = dB.x - lo, b1_ = dB.y - lo, b2_ = dB.z - lo, b3 = dB.w - lo;
            if ((unsigned)b0 < (unsigned)w) atomicAdd(&lhist[b0 >> 1], 1u << ((b0 & 1) * 16));
            if ((unsigned)b1_ < (unsigned)w) atomicAdd(&lhist[b1_ >> 1], 1u << ((b1_ & 1) * 16));
            if ((unsigned)b2_ < (unsigned)w) atomicAdd(&lhist[b2_ >> 1], 1u << ((b2_ & 1) * 16));
            if ((unsigned)b3 < (unsigned)w) atomicAdd(&lhist[b3 >> 1], 1u << ((b3 & 1) * 16));
        }
    }
    __syncthreads();
    int* gh = hist + ((size_t)r * NSTRIPE + j) * PACKED_W;
    for (int i = tid; i < PACKED_W; i += 512) gh[i] = lhist[i];
}

// ---------------- D2: scan ----------------

__global__ __launch_bounds__(256) void scan16_kernel(const int* __restrict__ hist,
                                                     int* __restrict__ row_start,
                                                     int* __restrict__ bsum, int N) {
    __shared__ int lds[256];
    int i = blockIdx.x * 256 + threadIdx.x;
    int v = 0;
    if (i < N) {
        int r = i / RANGE_W, loc = i - r * RANGE_W;
        const int* hp = hist + (size_t)r * NSTRIPE * PACKED_W + (loc >> 1);
        int sh = (loc & 1) * 16;
#pragma unroll 8
        for (int j = 0; j < NSTRIPE; ++j) v += (hp[j * PACKED_W] >> sh) & 0xffff;
    }
    lds[threadIdx.x] = v;
    __syncthreads();
    for (int off = 1; off < 256; off <<= 1) {
        int t = (threadIdx.x >= off) ? lds[threadIdx.x - off] : 0;
        __syncthreads();
        lds[threadIdx.x] += t;
        __syncthreads();
    }
    if (i < N) row_start[i] = lds[threadIdx.x] - v;
    if (threadIdx.x == 255) bsum[blockIdx.x] = lds[255];
}

// ---------------- D3: global prefix + absolute cursors ----------------

__global__ __launch_bounds__(256) void add_off_base_kernel(int* __restrict__ row_start,
                                                           const int* __restrict__ bsum,
                                                           const int* __restrict__ hist,
                                                           int* __restrict__ cur,
                                                           int N, int E) {
    __shared__ int lds[256];
    int b = blockIdx.x;
    lds[threadIdx.x] = (threadIdx.x < b) ? bsum[threadIdx.x] : 0;
    __syncthreads();
    for (int off = 128; off > 0; off >>= 1) {
        if (threadIdx.x < off) lds[threadIdx.x] += lds[threadIdx.x + off];
        __syncthreads();
    }
    int prefix = lds[0];
    int i = b * 256 + threadIdx.x;
    if (i < N) {
        int s = row_start[i] + prefix;
        row_start[i] = s;
        int r = i / RANGE_W, loc = i - r * RANGE_W;
        const int* hp = hist + (size_t)r * NSTRIPE * PACKED_W + (loc >> 1);
        int* cp = cur + (size_t)r * NSTRIPE * RANGE_W + loc;
        int sh = (loc & 1) * 16;
#pragma unroll 8
        for (int j = 0; j < NSTRIPE; ++j) {
            int h = (hp[j * PACKED_W] >> sh) & 0xffff;
            cp[j * RANGE_W] = s;
            s += h;
        }
    }
    if (b == 0 && threadIdx.x == 0) row_start[N] = E;
}

// ---------------- D4: scatter (packed edges) + GEMM-1 (backfill) ----------

__global__ __launch_bounds__(512) void scatter_gemm1_kernel(
    const unsigned* __restrict__ packed,
    const int* __restrict__ cur, int* __restrict__ csr_src, int E, int N,
    const float* __restrict__ x,
    const unsigned short* __restrict__ wt1l,
    const unsigned short* __restrict__ wt1r,
    const float* __restrict__ b1,
    unsigned short* __restrict__ Pl,
    unsigned short* __restrict__ Qr, int M) {
    __shared__ __align__(16) int lcur[RANGE_W];
    const int tid = threadIdx.x;
    if ((int)blockIdx.x >= NHIST) {
        gemm_body<128, true, 8>(blockIdx.x - NHIST, tid, x, wt1l, wt1r, b1, Pl, Qr, M);
        return;
    }
    const int b = blockIdx.x;
    const int r = b & (NRANGE - 1);
    const int j = b / NRANGE;
    const int lo = r * RANGE_W;
    const int w = min(N - lo, RANGE_W);
    const int* gb = cur + ((size_t)r * NSTRIPE + j) * RANGE_W;
    {
        int w4 = w & ~3;
        for (int i = tid * 4; i < w4; i += 2048)
            *(int4*)(&lcur[i]) = *(const int4*)(gb + i);
        for (int i = w4 + tid; i < w; i += 512) lcur[i] = gb[i];
    }
    __syncthreads();
    const int stripe = stripe_len(E);
    const int s0 = j * stripe;
    const int s1 = min(E, s0 + stripe);
    for (int e = s0 + tid * 4; e < s1; e += 4096) {
        uint4 pA = *(const uint4*)(packed + e);
        int eB = e + 2048;
        bool hb = eB < s1;
        uint4 pB = hb ? *(const uint4*)(packed + eB) : pA;
        int a0 = (int)(pA.x & 0xffffu) - lo, a1 = (int)(pA.y & 0xffffu) - lo;
        int a2 = (int)(pA.z & 0xffffu) - lo, a3 = (int)(pA.w & 0xffffu) - lo;
        if ((unsigned)a0 < (unsigned)w) { int p = atomicAdd(&lcur[a0], 1); csr_src[p] = (int)(pA.x >> 16); }
        if ((unsigned)a1 < (unsigned)w) { int p = atomicAdd(&lcur[a1], 1); csr_src[p] = (int)(pA.y >> 16); }
        if ((unsigned)a2 < (unsigned)w) { int p = atomicAdd(&lcur[a2], 1); csr_src[p] = (int)(pA.z >> 16); }
        if ((unsigned)a3 < (unsigned)w) { int p = atomicAdd(&lcur[a3], 1); csr_src[p] = (int)(pA.w >> 16); }
        if (hb) {
            int b0 = (int)(pB.x & 0xffffu) - lo, b1_ = (int)(pB.y & 0xffffu) - lo;
            int b2_ = (int)(pB.z & 0xffffu) - lo, b3 = (int)(pB.w & 0xffffu) - lo;
            if ((unsigned)b0 < (unsigned)w) { int p = atomicAdd(&lcur[b0], 1); csr_src[p] = (int)(pB.x >> 16); }
            if ((unsigned)b1_ < (unsigned)w) { int p = atomicAdd(&lcur[b1_], 1); csr_src[p] = (int)(pB.y >> 16); }
            if ((unsigned)b2_ < (unsigned)w) { int p = atomicAdd(&lcur[b2_], 1); csr_src[p] = (int)(pB.z >> 16); }
            if ((unsigned)b3 < (unsigned)w) { int p = atomicAdd(&lcur[b3], 1); csr_src[p] = (int)(pB.w >> 16); }
        }
    }
}

// ---------------- D5: agg1 + fused GEMM-2 ----------------
// Gather phase: 16 nodes/block, 4 nodes/wave, 16 lanes/node, 8ch(16B)/lane,
// 8-deep unroll. h = relu(mean(p[src]) + q) staged in LDS [16][136] (pad ->
// 2-way-free bank access). MFMA phase: wave w computes col-tile w of BOTH
// g = h@W2_l and r = h@W2_r + b2 (K=128 = 4 MFMAs each).
__global__ __launch_bounds__(256) void agg1_gemm2_kernel(
    const unsigned short* __restrict__ p,
    const unsigned short* __restrict__ q,
    const int* __restrict__ row_start,
    const int* __restrict__ csr_src,
    const unsigned short* __restrict__ wt2l,
    const unsigned short* __restrict__ wt2r,
    const float* __restrict__ b2,
    unsigned short* __restrict__ g,
    unsigned short* __restrict__ rbuf, int N) {
    __shared__ unsigned short hsh[16][136];
    int tid = threadIdx.x;
    int nl = tid >> 4;
    int lane = tid & 15;
    int n = blockIdx.x * 16 + nl;
    int na = min(n, N - 1);
    int s0 = row_start[na], s1 = row_start[na + 1];
    float acc[8] = {};
    const unsigned short* pc = p + lane * 8;
    int e = s0;
    for (; e + 7 < s1; e += 8) {
        uint4 v0 = *(const uint4*)(pc + (size_t)csr_src[e]     * 128);
        uint4 v1 = *(const uint4*)(pc + (size_t)csr_src[e + 1] * 128);
        uint4 v2 = *(const uint4*)(pc + (size_t)csr_src[e + 2] * 128);
        uint4 v3 = *(const uint4*)(pc + (size_t)csr_src[e + 3] * 128);
        uint4 v4 = *(const uint4*)(pc + (size_t)csr_src[e + 4] * 128);
        uint4 v5 = *(const uint4*)(pc + (size_t)csr_src[e + 5] * 128);
        uint4 v6 = *(const uint4*)(pc + (size_t)csr_src[e + 6] * 128);
        uint4 v7 = *(const uint4*)(pc + (size_t)csr_src[e + 7] * 128);
        acc[0] += ((bf_lo(v0.x) + bf_lo(v1.x)) + (bf_lo(v2.x) + bf_lo(v3.x)))
                + ((bf_lo(v4.x) + bf_lo(v5.x)) + (bf_lo(v6.x) + bf_lo(v7.x)));
        acc[1] += ((bf_hi(v0.x) + bf_hi(v1.x)) + (bf_hi(v2.x) + bf_hi(v3.x)))
                + ((bf_hi(v4.x) + bf_hi(v5.x)) + (bf_hi(v6.x) + bf_hi(v7.x)));
        acc[2] += ((bf_lo(v0.y) + bf_lo(v1.y)) + (bf_lo(v2.y) + bf_lo(v3.y)))
                + ((bf_lo(v4.y) + bf_lo(v5.y)) + (bf_lo(v6.y) + bf_lo(v7.y)));
        acc[3] += ((bf_hi(v0.y) + bf_hi(v1.y)) + (bf_hi(v2.y) + bf_hi(v3.y)))
                + ((bf_hi(v4.y) + bf_hi(v5.y)) + (bf_hi(v6.y) + bf_hi(v7.y)));
        acc[4] += ((bf_lo(v0.z) + bf_lo(v1.z)) + (bf_lo(v2.z) + bf_lo(v3.z)))
                + ((bf_lo(v4.z) + bf_lo(v5.z)) + (bf_lo(v6.z) + bf_lo(v7.z)));
        acc[5] += ((bf_hi(v0.z) + bf_hi(v1.z)) + (bf_hi(v2.z) + bf_hi(v3.z)))
                + ((bf_hi(v4.z) + bf_hi(v5.z)) + (bf_hi(v6.z) + bf_hi(v7.z)));
        acc[6] += ((bf_lo(v0.w) + bf_lo(v1.w)) + (bf_lo(v2.w) + bf_lo(v3.w)))
                + ((bf_lo(v4.w) + bf_lo(v5.w)) + (bf_lo(v6.w) + bf_lo(v7.w)));
        acc[7] += ((bf_hi(v0.w) + bf_hi(v1.w)) + (bf_hi(v2.w) + bf_hi(v3.w)))
                + ((bf_hi(v4.w) + bf_hi(v5.w)) + (bf_hi(v6.w) + bf_hi(v7.w)));
    }
    for (; e + 3 < s1; e += 4) {
        uint4 v0 = *(const uint4*)(pc + (size_t)csr_src[e]     * 128);
        uint4 v1 = *(const uint4*)(pc + (size_t)csr_src[e + 1] * 128);
        uint4 v2 = *(const uint4*)(pc + (size_t)csr_src[e + 2] * 128);
        uint4 v3 = *(const uint4*)(pc + (size_t)csr_src[e + 3] * 128);
        acc[0] += (bf_lo(v0.x) + bf_lo(v1.x)) + (bf_lo(v2.x) + bf_lo(v3.x));
        acc[1] += (bf_hi(v0.x) + bf_hi(v1.x)) + (bf_hi(v2.x) + bf_hi(v3.x));
        acc[2] += (bf_lo(v0.y) + bf_lo(v1.y)) + (bf_lo(v2.y) + bf_lo(v3.y));
        acc[3] += (bf_hi(v0.y) + bf_hi(v1.y)) + (bf_hi(v2.y) + bf_hi(v3.y));
        acc[4] += (bf_lo(v0.z) + bf_lo(v1.z)) + (bf_lo(v2.z) + bf_lo(v3.z));
        acc[5] += (bf_hi(v0.z) + bf_hi(v1.z)) + (bf_hi(v2.z) + bf_hi(v3.z));
        acc[6] += (bf_lo(v0.w) + bf_lo(v1.w)) + (bf_lo(v2.w) + bf_lo(v3.w));
        acc[7] += (bf_hi(v0.w) + bf_hi(v1.w)) + (bf_hi(v2.w) + bf_hi(v3.w));
    }
    for (; e < s1; ++e) {
        uint4 v0 = *(const uint4*)(pc + (size_t)csr_src[e] * 128);
        acc[0] += bf_lo(v0.x); acc[1] += bf_hi(v0.x);
        acc[2] += bf_lo(v0.y); acc[3] += bf_hi(v0.y);
        acc[4] += bf_lo(v0.z); acc[5] += bf_hi(v0.z);
        acc[6] += bf_lo(v0.w); acc[7] += bf_hi(v0.w);
    }
    float inv = 1.0f / (float)max(s1 - s0, 1);
    uint4 qv = *(const uint4*)(q + (size_t)na * 128 + lane * 8);
    float hv[8];
    hv[0] = fmaxf(fmaf(acc[0], inv, bf_lo(qv.x)), 0.f);
    hv[1] = fmaxf(fmaf(acc[1], inv, bf_hi(qv.x)), 0.f);
    hv[2] = fmaxf(fmaf(acc[2], inv, bf_lo(qv.y)), 0.f);
    hv[3] = fmaxf(fmaf(acc[3], inv, bf_hi(qv.y)), 0.f);
    hv[4] = fmaxf(fmaf(acc[4], inv, bf_lo(qv.z)), 0.f);
    hv[5] = fmaxf(fmaf(acc[5], inv, bf_hi(qv.z)), 0.f);
    hv[6] = fmaxf(fmaf(acc[6], inv, bf_lo(qv.w)), 0.f);
    hv[7] = fmaxf(fmaf(acc[7], inv, bf_hi(qv.w)), 0.f);
    uint4 o;
    o.x = packbf(hv[0], hv[1]); o.y = packbf(hv[2], hv[3]);
    o.z = packbf(hv[4], hv[5]); o.w = packbf(hv[6], hv[7]);
    *(uint4*)(&hsh[nl][lane * 8]) = o;
    __syncthreads();

    // ---- fused GEMM-2: g = h@W2_l, r = h@W2_r + b2 (16 rows x 64 cols) ----
    const int wave = tid >> 6;
    const int wl = tid & 63;
    const int lr = wl & 15;
    const int lk = wl >> 4;
#pragma unroll
    for (int mat = 0; mat < 2; ++mat) {
        const unsigned short* WT = mat ? wt2r : wt2l;
        const int ct = wave;   // col-tile 0..3
        f32x4 a2 = {0.f, 0.f, 0.f, 0.f};
#pragma unroll
        for (int s = 0; s < 4; ++s) {
            bf16x8 av = *(const bf16x8*)(&hsh[lr][lk * 8 + s * 32]);
            bf16x8 bv = *(const bf16x8*)(WT + (size_t)(ct * 16 + lr) * 128 + lk * 8 + s * 32);
            a2 = __builtin_amdgcn_mfma_f32_16x16x32_bf16(av, bv, a2, 0, 0, 0);
        }
        float bcol = mat ? b2[ct * 16 + lr] : 0.f;
#pragma unroll
        for (int rg = 0; rg < 4; ++rg) {
            int row = lk * 4 + rg;
            int gn = blockIdx.x * 16 + row;
            if (gn < N) {
                if (mat == 0)
                    g[(size_t)gn * 64 + ct * 16 + lr] = f2bf(a2[rg]);
                else
                    rbuf[(size_t)gn * 64 + ct * 16 + lr] = f2bf(a2[rg] + bcol);
            }
        }
    }
}

// ---------------- D6: agg2 ----------------
// out[n] = mean(g[src]) + r[n]; g,r bf16 (r includes b2); out f32; 64 ch.
__global__ __launch_bounds__(256) void agg2_kernel(const unsigned short* __restrict__ g,
                                                   const unsigned short* __restrict__ r,
                                                   const int* __restrict__ row_start,
                                                   const int* __restrict__ csr_src,
                                                   float* __restrict__ out, int N) {
    int tid = threadIdx.x;
    int n = blockIdx.x * 16 + (tid >> 4);
    int lane = tid & 15;
    if (n >= N) return;
    int s0 = row_start[n], s1 = row_start[n + 1];
    float acc[4] = {};
    const unsigned short* gc = g + lane * 4;
    int e = s0;
    for (; e + 7 < s1; e += 8) {
        uint2 v0 = *(const uint2*)(gc + (size_t)csr_src[e]     * 64);
        uint2 v1 = *(const uint2*)(gc + (size_t)csr_src[e + 1] * 64);
        uint2 v2 = *(const uint2*)(gc + (size_t)csr_src[e + 2] * 64);
        uint2 v3 = *(const uint2*)(gc + (size_t)csr_src[e + 3] * 64);
        uint2 v4 = *(const uint2*)(gc + (size_t)csr_src[e + 4] * 64);
        uint2 v5 = *(const uint2*)(gc + (size_t)csr_src[e + 5] * 64);
        uint2 v6 = *(const uint2*)(gc + (size_t)csr_src[e + 6] * 64);
        uint2 v7 = *(const uint2*)(gc + (size_t)csr_src[e + 7] * 64);
        acc[0] += ((bf_lo(v0.x) + bf_lo(v1.x)) + (bf_lo(v2.x) + bf_lo(v3.x)))
                + ((bf_lo(v4.x) + bf_lo(v5.x)) + (bf_lo(v6.x) + bf_lo(v7.x)));
        acc[1] += ((bf_hi(v0.x) + bf_hi(v1.x)) + (bf_hi(v2.x) + bf_hi(v3.x)))
                + ((bf_hi(v4.x) + bf_hi(v5.x)) + (bf_hi(v6.x) + bf_hi(v7.x)));
        acc[2] += ((bf_lo(v0.y) + bf_lo(v1.y)) + (bf_lo(v2.y) + bf_lo(v3.y)))
                + ((bf_lo(v4.y) + bf_lo(v5.y)) + (bf_lo(v6.y) + bf_lo(v7.y)));
        acc[3] += ((bf_hi(v0.y) + bf_hi(v1.y)) + (bf_hi(v2.y) + bf_hi(v3.y)))
                + ((bf_hi(v4.y) + bf_hi(v5.y)) + (bf_hi(v6.y) + bf_hi(v7.y)));
    }
    for (; e + 3 < s1; e += 4) {
        uint2 v0 = *(const uint2*)(gc + (size_t)csr_src[e]     * 64);
        uint2 v1 = *(const uint2*)(gc + (size_t)csr_src[e + 1] * 64);
        uint2 v2 = *(const uint2*)(gc + (size_t)csr_src[e + 2] * 64);
        uint2 v3 = *(const uint2*)(gc + (size_t)csr_src[e + 3] * 64);
        acc[0] += (bf_lo(v0.x) + bf_lo(v1.x)) + (bf_lo(v2.x) + bf_lo(v3.x));
        acc[1] += (bf_hi(v0.x) + bf_hi(v1.x)) + (bf_hi(v2.x) + bf_hi(v3.x));
        acc[2] += (bf_lo(v0.y) + bf_lo(v1.y)) + (bf_lo(v2.y) + bf_lo(v3.y));
        acc[3] += (bf_hi(v0.y) + bf_hi(v1.y)) + (bf_hi(v2.y) + bf_hi(v3.y));
    }
    for (; e < s1; ++e) {
        uint2 v0 = *(const uint2*)(gc + (size_t)csr_src[e] * 64);
        acc[0] += bf_lo(v0.x); acc[1] += bf_hi(v0.x);
        acc[2] += bf_lo(v0.y); acc[3] += bf_hi(v0.y);
    }
    float inv = 1.0f / (float)max(s1 - s0, 1);
    uint2 rv = *(const uint2*)(r + (size_t)n * 64 + lane * 4);
    float4 o;
    o.x = fmaf(acc[0], inv, bf_lo(rv.x));
    o.y = fmaf(acc[1], inv, bf_hi(rv.x));
    o.z = fmaf(acc[2], inv, bf_lo(rv.y));
    o.w = fmaf(acc[3], inv, bf_hi(rv.y));
    *(float4*)(out + (size_t)n * 64 + lane * 4) = o;
}

// ---------------------------------------------------------------------------

extern "C" void kernel_launch(void* const* d_in, const int* in_sizes, int n_in,
                              void* d_out, int out_size, void* d_ws, size_t ws_size,
                              hipStream_t stream) {
    const float* x    = (const float*)d_in[0];
    const int*   ei   = (const int*)d_in[1];
    const float* W1_l = (const float*)d_in[2];
    const float* b1   = (const float*)d_in[3];
    const float* W1_r = (const float*)d_in[4];
    const float* W2_l = (const float*)d_in[5];
    const float* b2   = (const float*)d_in[6];
    const float* W2_r = (const float*)d_in[7];

    const int N = in_sizes[0] / 128;   // 50000
    const int E = in_sizes[1] / 2;     // 800000
    const int* e_src = ei;
    const int* e_dst = ei + E;

    // ---- workspace layout ----
    char* ws = (char*)d_ws;
    auto align256 = [](size_t v) { return (v + 255) & ~(size_t)255; };
    size_t off = 0;
    int* row_start = (int*)(ws + off); off += align256((size_t)(N + 1) * 4);
    int* bsum      = (int*)(ws + off); off += align256(1024);
    int* hist      = (int*)(ws + off); off += align256((size_t)NRANGE * NSTRIPE * PACKED_W * 4);
    int* cur       = (int*)(ws + off); off += align256((size_t)NRANGE * NSTRIPE * RANGE_W * 4);
    unsigned* packed = (unsigned*)(ws + off); off += align256((size_t)E * 4);
    int* csr_src   = (int*)(ws + off); off += align256((size_t)E * 4);
    unsigned short* pg_bf = (unsigned short*)(ws + off); off += align256((size_t)N * 128 * 2); // p
    unsigned short* qr_bf = (unsigned short*)(ws + off); off += align256((size_t)N * 128 * 2); // q
    unsigned short* g_bf  = (unsigned short*)(ws + off); off += align256((size_t)N * 64 * 2);
    unsigned short* r_bf  = (unsigned short*)(ws + off); off += align256((size_t)N * 64 * 2);
    unsigned short* wt1l  = (unsigned short*)(ws + off); off += align256(128 * 128 * 2);
    unsigned short* wt1r  = (unsigned short*)(ws + off); off += align256(128 * 128 * 2);
    unsigned short* wt2l  = (unsigned short*)(ws + off); off += align256(128 * 64 * 2);
    unsigned short* wt2r  = (unsigned short*)(ws + off); off += align256(128 * 64 * 2);
    float* out = (float*)d_out;

    const int nb = (N + 255) / 256;
    const int nGemm1Wg = (N + 127) / 128;                 // 391 (128 rows/block)
    const int nWtWg = (16384 + 8192 + 511) / 512;         // 48

    // ---- D1: histogram + packed edges + weight prep (hist first, 512 thr) --
    hist_wt_kernel<<<NHIST + nWtWg, 512, 0, stream>>>(
        e_src, e_dst, hist, packed, E, N,
        W1_l, W1_r, W2_l, W2_r, wt1l, wt1r, wt2l, wt2r);
    // ---- D2/D3: CSR scan (no global atomics) ----
    scan16_kernel<<<nb, 256, 0, stream>>>(hist, row_start, bsum, N);
    add_off_base_kernel<<<nb, 256, 0, stream>>>(row_start, bsum, hist, cur, N, E);
    // ---- D4: scatter (packed) + GEMM-1 (p, q+b1) fused, scatter first ----
    scatter_gemm1_kernel<<<NHIST + nGemm1Wg, 512, 0, stream>>>(
        packed, cur, csr_src, E, N,
        x, wt1l, wt1r, b1, pg_bf, qr_bf, N);
    // ---- D5: agg1 + fused GEMM-2 (g, r+b2 written directly) ----
    agg1_gemm2_kernel<<<(N + 15) / 16, 256, 0, stream>>>(
        pg_bf, qr_bf, row_start, csr_src, wt2l, wt2r, b2, g_bf, r_bf, N);
    // ---- D6: agg2 ----
    agg2_kernel<<<(N + 15) / 16, 256, 0, stream>>>(g_bf, r_bf, row_start,
                                                   csr_src, out, N);
}

// Round 15
// 132.190 us; speedup vs baseline: 1.0833x; 1.0214x over previous
//
#include <hip/hip_runtime.h>
#include <hip/hip_bf16.h>

// ---------------------------------------------------------------------------
// GraphSAGE 2-layer forward.
//   h   = relu( mean_agg(x) @ W1_l + b1 + x @ W1_r )
//   out =       mean_agg(h) @ W2_l + b2 + h @ W2_r
// agg(x)@W == agg(x@W): transform-then-aggregate. Biases folded into GEMM
// epilogues (q = x@W1_r + b1, r = h@W2_r + b2).
// bf16 MFMA GEMMs with SWAPPED operands: mfma(W-frag, x-frag) -> lane holds
// 4 consecutive output channels of one row -> ushort4 epilogue stores
// (16 store instrs/wave instead of 128 scalar shorts).
// CSR build with ZERO global atomics; NRANGE=8, NSTRIPE=64:
//   D1 hist+wt (512 thr): packed 2xushort LDS hist (12.5 KB); range-0
//      blocks emit packed edges (src16|dst16); weight-transpose backfills.
//   D2 scan16 / D3 add_off_base: row_start + absolute cursors.
//   D4 scatter+GEMM1 (512 thr): 512 scatter blocks first (25 KB LDS
//      cursors, LDS-atomic pos, plain stores); GEMM-1 (128 rows) backfills.
//   D5 agg1 + fused GEMM-2 (no h round-trip).
//   D6 agg2.
// ---------------------------------------------------------------------------

typedef __attribute__((ext_vector_type(8))) short bf16x8;
typedef __attribute__((ext_vector_type(4))) float f32x4;

static __device__ __forceinline__ float bf_lo(unsigned u) {
    u <<= 16; return __builtin_bit_cast(float, u);
}
static __device__ __forceinline__ float bf_hi(unsigned u) {
    u &= 0xffff0000u; return __builtin_bit_cast(float, u);
}
static __device__ __forceinline__ unsigned short f2bf(float f) {
    __hip_bfloat16 b = __float2bfloat16(f);
    return __builtin_bit_cast(unsigned short, b);
}
static __device__ __forceinline__ unsigned packbf(float lo, float hi) {
    return (unsigned)f2bf(lo) | ((unsigned)f2bf(hi) << 16);
}

#define NRANGE   8
#define RANGE_W  6250      // N == 8*6250 exactly
#define PACKED_W 3125      // RANGE_W/2, two ushort counts per int
#define NSTRIPE  64
#define NHIST    (NRANGE * NSTRIPE)   // 512

static __device__ __forceinline__ int stripe_len(int E) {
    return ((E / NSTRIPE) + 3) & ~3;  // multiple of 4 for int4 alignment
}

// ---------------- MFMA dual GEMM body (swapped operands) ----------------
// A[M][128] row-major (fp32 if A_F32 else bf16); WTl/WTr[NC][128] bf16 (=W^T).
// mfma(W-frag, x-frag): D lane l = out[row m0+(l&15)][ch ct*16+(l>>4)*4+reg]
// -> ushort4 store of 4 consecutive channels. Pl = A@Wl, Qr = A@Wr + bias.

template <int NC, bool A_F32, int WPB>
static __device__ __forceinline__ void gemm_body(
    int bid, int tid, const void* __restrict__ Av,
    const unsigned short* __restrict__ WTl,
    const unsigned short* __restrict__ WTr,
    const float* __restrict__ bias,
    unsigned short* __restrict__ Pl,
    unsigned short* __restrict__ Qr, int M) {
    const int wave = tid >> 6;
    const int lane = tid & 63;
    const int m0 = bid * (WPB * 16) + wave * 16;
    const int lr = lane & 15;
    const int lk = lane >> 4;

    int arow = m0 + lr;
    if (arow >= M) arow = M - 1;
    const bool rowok = (m0 + lr) < M;

    bf16x8 xf[4];
    if (A_F32) {
        const float* Ab = (const float*)Av + (size_t)arow * 128 + lk * 8;
#pragma unroll
        for (int s = 0; s < 4; ++s) {
            float4 v0 = *(const float4*)(Ab + s * 32);
            float4 v1 = *(const float4*)(Ab + s * 32 + 4);
            unsigned short t[8] = {f2bf(v0.x), f2bf(v0.y), f2bf(v0.z), f2bf(v0.w),
                                   f2bf(v1.x), f2bf(v1.y), f2bf(v1.z), f2bf(v1.w)};
            xf[s] = *(const bf16x8*)t;
        }
    } else {
        const unsigned short* Ab = (const unsigned short*)Av + (size_t)arow * 128 + lk * 8;
#pragma unroll
        for (int s = 0; s < 4; ++s) xf[s] = *(const bf16x8*)(Ab + s * 32);
    }

#pragma unroll
    for (int ct = 0; ct < NC / 16; ++ct) {
        const unsigned short* Bl = WTl + (size_t)(ct * 16 + lr) * 128 + lk * 8;
        const unsigned short* Br = WTr + (size_t)(ct * 16 + lr) * 128 + lk * 8;
        f32x4 accL = {0.f, 0.f, 0.f, 0.f};
        f32x4 accR = {0.f, 0.f, 0.f, 0.f};
#pragma unroll
        for (int s = 0; s < 4; ++s) {
            bf16x8 bl = *(const bf16x8*)(Bl + s * 32);
            bf16x8 br = *(const bf16x8*)(Br + s * 32);
            accL = __builtin_amdgcn_mfma_f32_16x16x32_bf16(bl, xf[s], accL, 0, 0, 0);
            accR = __builtin_amdgcn_mfma_f32_16x16x32_bf16(br, xf[s], accR, 0, 0, 0);
        }
        if (rowok) {
            float4 b4 = *(const float4*)(bias + ct * 16 + lk * 4);
            ushort4 oL, oR;
            oL.x = f2bf(accL[0]); oL.y = f2bf(accL[1]);
            oL.z = f2bf(accL[2]); oL.w = f2bf(accL[3]);
            oR.x = f2bf(accR[0] + b4.x); oR.y = f2bf(accR[1] + b4.y);
            oR.z = f2bf(accR[2] + b4.z); oR.w = f2bf(accR[3] + b4.w);
            size_t base = (size_t)(m0 + lr) * NC + ct * 16 + lk * 4;
            *(ushort4*)(Pl + base) = oL;
            *(ushort4*)(Qr + base) = oR;
        }
    }
}

// ---------------- D1: hist + packed-edge emit + weight prep ----------------

__global__ __launch_bounds__(512) void hist_wt_kernel(
    const int* __restrict__ src, const int* __restrict__ dst,
    int* __restrict__ hist, unsigned* __restrict__ packed, int E, int N,
    const float* __restrict__ W1l, const float* __restrict__ W1r,
    const float* __restrict__ W2l, const float* __restrict__ W2r,
    unsigned short* __restrict__ T1l, unsigned short* __restrict__ T1r,
    unsigned short* __restrict__ T2l, unsigned short* __restrict__ T2r) {
    __shared__ int lhist[PACKED_W];
    const int tid = threadIdx.x;
    if ((int)blockIdx.x >= NHIST) {
        int i = (blockIdx.x - NHIST) * 512 + tid;
        if (i < 16384) {
            int k = i >> 7, n = i & 127;
            T1l[n * 128 + k] = f2bf(W1l[i]);
            T1r[n * 128 + k] = f2bf(W1r[i]);
        } else if (i < 16384 + 8192) {
            int m = i - 16384;
            int k = m >> 6, n = m & 63;
            T2l[n * 128 + k] = f2bf(W2l[m]);
            T2r[n * 128 + k] = f2bf(W2r[m]);
        }
        return;
    }
    const int b = blockIdx.x;
    const int r = b & (NRANGE - 1);
    const int j = b >> 3;
    const int lo = r * RANGE_W;
    const int w = min(N - lo, RANGE_W);
    for (int i = tid; i < PACKED_W; i += 512) lhist[i] = 0;
    __syncthreads();
    const int stripe = stripe_len(E);
    const int s0 = j * stripe;
    const int s1 = min(E, s0 + stripe);
    for (int e = s0 + tid * 4; e < s1; e += 2048) {
        int4 dA = *(const int4*)(dst + e);
        if (r == 0) {
            int4 sA = *(const int4*)(src + e);
            uint4 pA;
            pA.x = ((unsigned)sA.x << 16) | (unsigned)dA.x;
            pA.y = ((unsigned)sA.y << 16) | (unsigned)dA.y;
            pA.z = ((unsigned)sA.z << 16) | (unsigned)dA.z;
            pA.w = ((unsigned)sA.w << 16) | (unsigned)dA.w;
            *(uint4*)(packed + e) = pA;
        }
        int a0 = dA.x - lo, a1 = dA.y - lo, a2 = dA.z - lo, a3 = dA.w - lo;
        if ((unsigned)a0 < (unsigned)w) atomicAdd(&lhist[a0 >> 1], 1u << ((a0 & 1) * 16));
        if ((unsigned)a1 < (unsigned)w) atomicAdd(&lhist[a1 >> 1], 1u << ((a1 & 1) * 16));
        if ((unsigned)a2 < (unsigned)w) atomicAdd(&lhist[a2 >> 1], 1u << ((a2 & 1) * 16));
        if ((unsigned)a3 < (unsigned)w) atomicAdd(&lhist[a3 >> 1], 1u << ((a3 & 1) * 16));
    }
    __syncthreads();
    int* gh = hist + ((size_t)r * NSTRIPE + j) * PACKED_W;
    for (int i = tid; i < PACKED_W; i += 512) gh[i] = lhist[i];
}

// ---------------- D2: scan ----------------

__global__ __launch_bounds__(256) void scan16_kernel(const int* __restrict__ hist,
                                                     int* __restrict__ row_start,
                                                     int* __restrict__ bsum, int N) {
    __shared__ int lds[256];
    int i = blockIdx.x * 256 + threadIdx.x;
    int v = 0;
    if (i < N) {
        int r = i / RANGE_W, loc = i - r * RANGE_W;
        const int* hp = hist + (size_t)r * NSTRIPE * PACKED_W + (loc >> 1);
        int sh = (loc & 1) * 16;
#pragma unroll 8
        for (int j = 0; j < NSTRIPE; ++j) v += (hp[j * PACKED_W] >> sh) & 0xffff;
    }
    lds[threadIdx.x] = v;
    __syncthreads();
    for (int off = 1; off < 256; off <<= 1) {
        int t = (threadIdx.x >= off) ? lds[threadIdx.x - off] : 0;
        __syncthreads();
        lds[threadIdx.x] += t;
        __syncthreads();
    }
    if (i < N) row_start[i] = lds[threadIdx.x] - v;
    if (threadIdx.x == 255) bsum[blockIdx.x] = lds[255];
}

// ---------------- D3: global prefix + absolute cursors ----------------

__global__ __launch_bounds__(256) void add_off_base_kernel(int* __restrict__ row_start,
                                                           const int* __restrict__ bsum,
                                                           const int* __restrict__ hist,
                                                           int* __restrict__ cur,
                                                           int N, int E) {
    __shared__ int lds[256];
    int b = blockIdx.x;
    lds[threadIdx.x] = (threadIdx.x < b) ? bsum[threadIdx.x] : 0;
    __syncthreads();
    for (int off = 128; off > 0; off >>= 1) {
        if (threadIdx.x < off) lds[threadIdx.x] += lds[threadIdx.x + off];
        __syncthreads();
    }
    int prefix = lds[0];
    int i = b * 256 + threadIdx.x;
    if (i < N) {
        int s = row_start[i] + prefix;
        row_start[i] = s;
        int r = i / RANGE_W, loc = i - r * RANGE_W;
        const int* hp = hist + (size_t)r * NSTRIPE * PACKED_W + (loc >> 1);
        int* cp = cur + (size_t)r * NSTRIPE * RANGE_W + loc;
        int sh = (loc & 1) * 16;
#pragma unroll 8
        for (int j = 0; j < NSTRIPE; ++j) {
            int h = (hp[j * PACKED_W] >> sh) & 0xffff;
            cp[j * RANGE_W] = s;
            s += h;
        }
    }
    if (b == 0 && threadIdx.x == 0) row_start[N] = E;
}

// ---------------- D4: scatter (packed edges) + GEMM-1 (backfill) ----------

__global__ __launch_bounds__(512) void scatter_gemm1_kernel(
    const unsigned* __restrict__ packed,
    const int* __restrict__ cur, int* __restrict__ csr_src, int E, int N,
    const float* __restrict__ x,
    const unsigned short* __restrict__ wt1l,
    const unsigned short* __restrict__ wt1r,
    const float* __restrict__ b1,
    unsigned short* __restrict__ Pl,
    unsigned short* __restrict__ Qr, int M) {
    __shared__ __align__(16) int lcur[RANGE_W];
    const int tid = threadIdx.x;
    if ((int)blockIdx.x >= NHIST) {
        gemm_body<128, true, 8>(blockIdx.x - NHIST, tid, x, wt1l, wt1r, b1, Pl, Qr, M);
        return;
    }
    const int b = blockIdx.x;
    const int r = b & (NRANGE - 1);
    const int j = b >> 3;
    const int lo = r * RANGE_W;
    const int w = min(N - lo, RANGE_W);
    const int* gb = cur + ((size_t)r * NSTRIPE + j) * RANGE_W;
    {
        int w4 = w & ~3;
        for (int i = tid * 4; i < w4; i += 2048)
            *(int4*)(&lcur[i]) = *(const int4*)(gb + i);
        for (int i = w4 + tid; i < w; i += 512) lcur[i] = gb[i];
    }
    __syncthreads();
    const int stripe = stripe_len(E);
    const int s0 = j * stripe;
    const int s1 = min(E, s0 + stripe);
    for (int e = s0 + tid * 4; e < s1; e += 2048) {
        uint4 pA = *(const uint4*)(packed + e);
        int a0 = (int)(pA.x & 0xffffu) - lo, a1 = (int)(pA.y & 0xffffu) - lo;
        int a2 = (int)(pA.z & 0xffffu) - lo, a3 = (int)(pA.w & 0xffffu) - lo;
        if ((unsigned)a0 < (unsigned)w) { int p = atomicAdd(&lcur[a0], 1); csr_src[p] = (int)(pA.x >> 16); }
        if ((unsigned)a1 < (unsigned)w) { int p = atomicAdd(&lcur[a1], 1); csr_src[p] = (int)(pA.y >> 16); }
        if ((unsigned)a2 < (unsigned)w) { int p = atomicAdd(&lcur[a2], 1); csr_src[p] = (int)(pA.z >> 16); }
        if ((unsigned)a3 < (unsigned)w) { int p = atomicAdd(&lcur[a3], 1); csr_src[p] = (int)(pA.w >> 16); }
    }
}

// ---------------- D5: agg1 + fused GEMM-2 (swapped operands) ----------------
// Gather: 16 nodes/block, 4 nodes/wave, 16 lanes/node, 8ch(16B)/lane, 8-deep.
// h staged in LDS [16][136]. MFMA: wave ct computes col-tile ct of g and r;
// lane holds 4 consecutive channels of h-row lr -> ushort4 stores.
__global__ __launch_bounds__(256) void agg1_gemm2_kernel(
    const unsigned short* __restrict__ p,
    const unsigned short* __restrict__ q,
    const int* __restrict__ row_start,
    const int* __restrict__ csr_src,
    const unsigned short* __restrict__ wt2l,
    const unsigned short* __restrict__ wt2r,
    const float* __restrict__ b2,
    unsigned short* __restrict__ g,
    unsigned short* __restrict__ rbuf, int N) {
    __shared__ unsigned short hsh[16][136];
    int tid = threadIdx.x;
    int nl = tid >> 4;
    int lane = tid & 15;
    int n = blockIdx.x * 16 + nl;
    int na = min(n, N - 1);
    int s0 = row_start[na], s1 = row_start[na + 1];
    float acc[8] = {};
    const unsigned short* pc = p + lane * 8;
    int e = s0;
    for (; e + 7 < s1; e += 8) {
        uint4 v0 = *(const uint4*)(pc + (size_t)csr_src[e]     * 128);
        uint4 v1 = *(const uint4*)(pc + (size_t)csr_src[e + 1] * 128);
        uint4 v2 = *(const uint4*)(pc + (size_t)csr_src[e + 2] * 128);
        uint4 v3 = *(const uint4*)(pc + (size_t)csr_src[e + 3] * 128);
        uint4 v4 = *(const uint4*)(pc + (size_t)csr_src[e + 4] * 128);
        uint4 v5 = *(const uint4*)(pc + (size_t)csr_src[e + 5] * 128);
        uint4 v6 = *(const uint4*)(pc + (size_t)csr_src[e + 6] * 128);
        uint4 v7 = *(const uint4*)(pc + (size_t)csr_src[e + 7] * 128);
        acc[0] += ((bf_lo(v0.x) + bf_lo(v1.x)) + (bf_lo(v2.x) + bf_lo(v3.x)))
                + ((bf_lo(v4.x) + bf_lo(v5.x)) + (bf_lo(v6.x) + bf_lo(v7.x)));
        acc[1] += ((bf_hi(v0.x) + bf_hi(v1.x)) + (bf_hi(v2.x) + bf_hi(v3.x)))
                + ((bf_hi(v4.x) + bf_hi(v5.x)) + (bf_hi(v6.x) + bf_hi(v7.x)));
        acc[2] += ((bf_lo(v0.y) + bf_lo(v1.y)) + (bf_lo(v2.y) + bf_lo(v3.y)))
                + ((bf_lo(v4.y) + bf_lo(v5.y)) + (bf_lo(v6.y) + bf_lo(v7.y)));
        acc[3] += ((bf_hi(v0.y) + bf_hi(v1.y)) + (bf_hi(v2.y) + bf_hi(v3.y)))
                + ((bf_hi(v4.y) + bf_hi(v5.y)) + (bf_hi(v6.y) + bf_hi(v7.y)));
        acc[4] += ((bf_lo(v0.z) + bf_lo(v1.z)) + (bf_lo(v2.z) + bf_lo(v3.z)))
                + ((bf_lo(v4.z) + bf_lo(v5.z)) + (bf_lo(v6.z) + bf_lo(v7.z)));
        acc[5] += ((bf_hi(v0.z) + bf_hi(v1.z)) + (bf_hi(v2.z) + bf_hi(v3.z)))
                + ((bf_hi(v4.z) + bf_hi(v5.z)) + (bf_hi(v6.z) + bf_hi(v7.z)));
        acc[6] += ((bf_lo(v0.w) + bf_lo(v1.w)) + (bf_lo(v2.w) + bf_lo(v3.w)))
                + ((bf_lo(v4.w) + bf_lo(v5.w)) + (bf_lo(v6.w) + bf_lo(v7.w)));
        acc[7] += ((bf_hi(v0.w) + bf_hi(v1.w)) + (bf_hi(v2.w) + bf_hi(v3.w)))
                + ((bf_hi(v4.w) + bf_hi(v5.w)) + (bf_hi(v6.w) + bf_hi(v7.w)));
    }
    for (; e + 3 < s1; e += 4) {
        uint4 v0 = *(const uint4*)(pc + (size_t)csr_src[e]     * 128);
        uint4 v1 = *(const uint4*)(pc + (size_t)csr_src[e + 1] * 128);
        uint4 v2 = *(const uint4*)(pc + (size_t)csr_src[e + 2] * 128);
        uint4 v3 = *(const uint4*)(pc + (size_t)csr_src[e + 3] * 128);
        acc[0] += (bf_lo(v0.x) + bf_lo(v1.x)) + (bf_lo(v2.x) + bf_lo(v3.x));
        acc[1] += (bf_hi(v0.x) + bf_hi(v1.x)) + (bf_hi(v2.x) + bf_hi(v3.x));
        acc[2] += (bf_lo(v0.y) + bf_lo(v1.y)) + (bf_lo(v2.y) + bf_lo(v3.y));
        acc[3] += (bf_hi(v0.y) + bf_hi(v1.y)) + (bf_hi(v2.y) + bf_hi(v3.y));
        acc[4] += (bf_lo(v0.z) + bf_lo(v1.z)) + (bf_lo(v2.z) + bf_lo(v3.z));
        acc[5] += (bf_hi(v0.z) + bf_hi(v1.z)) + (bf_hi(v2.z) + bf_hi(v3.z));
        acc[6] += (bf_lo(v0.w) + bf_lo(v1.w)) + (bf_lo(v2.w) + bf_lo(v3.w));
        acc[7] += (bf_hi(v0.w) + bf_hi(v1.w)) + (bf_hi(v2.w) + bf_hi(v3.w));
    }
    for (; e < s1; ++e) {
        uint4 v0 = *(const uint4*)(pc + (size_t)csr_src[e] * 128);
        acc[0] += bf_lo(v0.x); acc[1] += bf_hi(v0.x);
        acc[2] += bf_lo(v0.y); acc[3] += bf_hi(v0.y);
        acc[4] += bf_lo(v0.z); acc[5] += bf_hi(v0.z);
        acc[6] += bf_lo(v0.w); acc[7] += bf_hi(v0.w);
    }
    float inv = 1.0f / (float)max(s1 - s0, 1);
    uint4 qv = *(const uint4*)(q + (size_t)na * 128 + lane * 8);
    float hv[8];
    hv[0] = fmaxf(fmaf(acc[0], inv, bf_lo(qv.x)), 0.f);
    hv[1] = fmaxf(fmaf(acc[1], inv, bf_hi(qv.x)), 0.f);
    hv[2] = fmaxf(fmaf(acc[2], inv, bf_lo(qv.y)), 0.f);
    hv[3] = fmaxf(fmaf(acc[3], inv, bf_hi(qv.y)), 0.f);
    hv[4] = fmaxf(fmaf(acc[4], inv, bf_lo(qv.z)), 0.f);
    hv[5] = fmaxf(fmaf(acc[5], inv, bf_hi(qv.z)), 0.f);
    hv[6] = fmaxf(fmaf(acc[6], inv, bf_lo(qv.w)), 0.f);
    hv[7] = fmaxf(fmaf(acc[7], inv, bf_hi(qv.w)), 0.f);
    uint4 o;
    o.x = packbf(hv[0], hv[1]); o.y = packbf(hv[2], hv[3]);
    o.z = packbf(hv[4], hv[5]); o.w = packbf(hv[6], hv[7]);
    *(uint4*)(&hsh[nl][lane * 8]) = o;
    __syncthreads();

    // ---- fused GEMM-2 (swapped): g = h@W2_l, r = h@W2_r + b2 ----
    const int wave = tid >> 6;
    const int wl = tid & 63;
    const int lr = wl & 15;
    const int lk = wl >> 4;
    const int gn = blockIdx.x * 16 + lr;
    const bool rowok = gn < N;
    const int ct = wave;   // col-tile 0..3
    f32x4 aL = {0.f, 0.f, 0.f, 0.f};
    f32x4 aR = {0.f, 0.f, 0.f, 0.f};
#pragma unroll
    for (int s = 0; s < 4; ++s) {
        bf16x8 hvv = *(const bf16x8*)(&hsh[lr][lk * 8 + s * 32]);
        bf16x8 bl = *(const bf16x8*)(wt2l + (size_t)(ct * 16 + lr) * 128 + lk * 8 + s * 32);
        bf16x8 br = *(const bf16x8*)(wt2r + (size_t)(ct * 16 + lr) * 128 + lk * 8 + s * 32);
        aL = __builtin_amdgcn_mfma_f32_16x16x32_bf16(bl, hvv, aL, 0, 0, 0);
        aR = __builtin_amdgcn_mfma_f32_16x16x32_bf16(br, hvv, aR, 0, 0, 0);
    }
    if (rowok) {
        float4 b4 = *(const float4*)(b2 + ct * 16 + lk * 4);
        ushort4 oL, oR;
        oL.x = f2bf(aL[0]); oL.y = f2bf(aL[1]); oL.z = f2bf(aL[2]); oL.w = f2bf(aL[3]);
        oR.x = f2bf(aR[0] + b4.x); oR.y = f2bf(aR[1] + b4.y);
        oR.z = f2bf(aR[2] + b4.z); oR.w = f2bf(aR[3] + b4.w);
        size_t base = (size_t)gn * 64 + ct * 16 + lk * 4;
        *(ushort4*)(g + base) = oL;
        *(ushort4*)(rbuf + base) = oR;
    }
}

// ---------------- D6: agg2 ----------------

__global__ __launch_bounds__(256) void agg2_kernel(const unsigned short* __restrict__ g,
                                                   const unsigned short* __restrict__ r,
                                                   const int* __restrict__ row_start,
                                                   const int* __restrict__ csr_src,
                                                   float* __restrict__ out, int N) {
    int tid = threadIdx.x;
    int n = blockIdx.x * 16 + (tid >> 4);
    int lane = tid & 15;
    if (n >= N) return;
    int s0 = row_start[n], s1 = row_start[n + 1];
    float acc[4] = {};
    const unsigned short* gc = g + lane * 4;
    int e = s0;
    for (; e + 7 < s1; e += 8) {
        uint2 v0 = *(const uint2*)(gc + (size_t)csr_src[e]     * 64);
        uint2 v1 = *(const uint2*)(gc + (size_t)csr_src[e + 1] * 64);
        uint2 v2 = *(const uint2*)(gc + (size_t)csr_src[e + 2] * 64);
        uint2 v3 = *(const uint2*)(gc + (size_t)csr_src[e + 3] * 64);
        uint2 v4 = *(const uint2*)(gc + (size_t)csr_src[e + 4] * 64);
        uint2 v5 = *(const uint2*)(gc + (size_t)csr_src[e + 5] * 64);
        uint2 v6 = *(const uint2*)(gc + (size_t)csr_src[e + 6] * 64);
        uint2 v7 = *(const uint2*)(gc + (size_t)csr_src[e + 7] * 64);
        acc[0] += ((bf_lo(v0.x) + bf_lo(v1.x)) + (bf_lo(v2.x) + bf_lo(v3.x)))
                + ((bf_lo(v4.x) + bf_lo(v5.x)) + (bf_lo(v6.x) + bf_lo(v7.x)));
        acc[1] += ((bf_hi(v0.x) + bf_hi(v1.x)) + (bf_hi(v2.x) + bf_hi(v3.x)))
                + ((bf_hi(v4.x) + bf_hi(v5.x)) + (bf_hi(v6.x) + bf_hi(v7.x)));
        acc[2] += ((bf_lo(v0.y) + bf_lo(v1.y)) + (bf_lo(v2.y) + bf_lo(v3.y)))
                + ((bf_lo(v4.y) + bf_lo(v5.y)) + (bf_lo(v6.y) + bf_lo(v7.y)));
        acc[3] += ((bf_hi(v0.y) + bf_hi(v1.y)) + (bf_hi(v2.y) + bf_hi(v3.y)))
                + ((bf_hi(v4.y) + bf_hi(v5.y)) + (bf_hi(v6.y) + bf_hi(v7.y)));
    }
    for (; e + 3 < s1; e += 4) {
        uint2 v0 = *(const uint2*)(gc + (size_t)csr_src[e]     * 64);
        uint2 v1 = *(const uint2*)(gc + (size_t)csr_src[e + 1] * 64);
        uint2 v2 = *(const uint2*)(gc + (size_t)csr_src[e + 2] * 64);
        uint2 v3 = *(const uint2*)(gc + (size_t)csr_src[e + 3] * 64);
        acc[0] += (bf_lo(v0.x) + bf_lo(v1.x)) + (bf_lo(v2.x) + bf_lo(v3.x));
        acc[1] += (bf_hi(v0.x) + bf_hi(v1.x)) + (bf_hi(v2.x) + bf_hi(v3.x));
        acc[2] += (bf_lo(v0.y) + bf_lo(v1.y)) + (bf_lo(v2.y) + bf_lo(v3.y));
        acc[3] += (bf_hi(v0.y) + bf_hi(v1.y)) + (bf_hi(v2.y) + bf_hi(v3.y));
    }
    for (; e < s1; ++e) {
        uint2 v0 = *(const uint2*)(gc + (size_t)csr_src[e] * 64);
        acc[0] += bf_lo(v0.x); acc[1] += bf_hi(v0.x);
        acc[2] += bf_lo(v0.y); acc[3] += bf_hi(v0.y);
    }
    float inv = 1.0f / (float)max(s1 - s0, 1);
    uint2 rv = *(const uint2*)(r + (size_t)n * 64 + lane * 4);
    float4 o;
    o.x = fmaf(acc[0], inv, bf_lo(rv.x));
    o.y = fmaf(acc[1], inv, bf_hi(rv.x));
    o.z = fmaf(acc[2], inv, bf_lo(rv.y));
    o.w = fmaf(acc[3], inv, bf_hi(rv.y));
    *(float4*)(out + (size_t)n * 64 + lane * 4) = o;
}

// ---------------------------------------------------------------------------

extern "C" void kernel_launch(void* const* d_in, const int* in_sizes, int n_in,
                              void* d_out, int out_size, void* d_ws, size_t ws_size,
                              hipStream_t stream) {
    const float* x    = (const float*)d_in[0];
    const int*   ei   = (const int*)d_in[1];
    const float* W1_l = (const float*)d_in[2];
    const float* b1   = (const float*)d_in[3];
    const float* W1_r = (const float*)d_in[4];
    const float* W2_l = (const float*)d_in[5];
    const float* b2   = (const float*)d_in[6];
    const float* W2_r = (const float*)d_in[7];

    const int N = in_sizes[0] / 128;   // 50000
    const int E = in_sizes[1] / 2;     // 800000
    const int* e_src = ei;
    const int* e_dst = ei + E;

    // ---- workspace layout ----
    char* ws = (char*)d_ws;
    auto align256 = [](size_t v) { return (v + 255) & ~(size_t)255; };
    size_t off = 0;
    int* row_start = (int*)(ws + off); off += align256((size_t)(N + 1) * 4);
    int* bsum      = (int*)(ws + off); off += align256(1024);
    int* hist      = (int*)(ws + off); off += align256((size_t)NRANGE * NSTRIPE * PACKED_W * 4);
    int* cur       = (int*)(ws + off); off += align256((size_t)NRANGE * NSTRIPE * RANGE_W * 4);
    unsigned* packed = (unsigned*)(ws + off); off += align256((size_t)E * 4);
    int* csr_src   = (int*)(ws + off); off += align256((size_t)E * 4);
    unsigned short* pg_bf = (unsigned short*)(ws + off); off += align256((size_t)N * 128 * 2); // p
    unsigned short* qr_bf = (unsigned short*)(ws + off); off += align256((size_t)N * 128 * 2); // q
    unsigned short* g_bf  = (unsigned short*)(ws + off); off += align256((size_t)N * 64 * 2);
    unsigned short* r_bf  = (unsigned short*)(ws + off); off += align256((size_t)N * 64 * 2);
    unsigned short* wt1l  = (unsigned short*)(ws + off); off += align256(128 * 128 * 2);
    unsigned short* wt1r  = (unsigned short*)(ws + off); off += align256(128 * 128 * 2);
    unsigned short* wt2l  = (unsigned short*)(ws + off); off += align256(128 * 64 * 2);
    unsigned short* wt2r  = (unsigned short*)(ws + off); off += align256(128 * 64 * 2);
    float* out = (float*)d_out;

    const int nb = (N + 255) / 256;
    const int nGemm1Wg = (N + 127) / 128;                 // 391 (128 rows/block)
    const int nWtWg = (16384 + 8192 + 511) / 512;         // 48

    // ---- D1: histogram + packed edges + weight prep (hist first, 512 thr) --
    hist_wt_kernel<<<NHIST + nWtWg, 512, 0, stream>>>(
        e_src, e_dst, hist, packed, E, N,
        W1_l, W1_r, W2_l, W2_r, wt1l, wt1r, wt2l, wt2r);
    // ---- D2/D3: CSR scan (no global atomics) ----
    scan16_kernel<<<nb, 256, 0, stream>>>(hist, row_start, bsum, N);
    add_off_base_kernel<<<nb, 256, 0, stream>>>(row_start, bsum, hist, cur, N, E);
    // ---- D4: scatter (packed) + GEMM-1 (p, q+b1) fused, scatter first ----
    scatter_gemm1_kernel<<<NHIST + nGemm1Wg, 512, 0, stream>>>(
        packed, cur, csr_src, E, N,
        x, wt1l, wt1r, b1, pg_bf, qr_bf, N);
    // ---- D5: agg1 + fused GEMM-2 (g, r+b2 written directly) ----
    agg1_gemm2_kernel<<<(N + 15) / 16, 256, 0, stream>>>(
        pg_bf, qr_bf, row_start, csr_src, wt2l, wt2r, b2, g_bf, r_bf, N);
    // ---- D6: agg2 ----
    agg2_kernel<<<(N + 15) / 16, 256, 0, stream>>>(g_bf, r_bf, row_start,
                                                   csr_src, out, N);
}

// Round 17
// 118.907 us; speedup vs baseline: 1.2043x; 1.1117x over previous
//
#include <hip/hip_runtime.h>
#include <hip/hip_bf16.h>
#include <hip/hip_fp8.h>

// ---------------------------------------------------------------------------
// GraphSAGE 2-layer forward.
//   h   = relu( mean_agg(x) @ W1_l + b1 + x @ W1_r )
//   out =       mean_agg(h) @ W2_l + b2 + h @ W2_r
// agg(x)@W == agg(x@W): transform-then-aggregate. Biases folded into GEMM
// epilogues (q = x@W1_r + b1, r = h@W2_r + b2).
// MFMA GEMMs with swapped operands (lane holds 4 consecutive out channels).
// Precision: p (layer-1 gather buffer) fp8 e4m3 -> halves the dominant
// gather traffic; q,r,g,h bf16; out fp32. csr_src ushort.
// CSR build with ZERO global atomics; NRANGE=8, NSTRIPE=64 (pinned cfg).
// ---------------------------------------------------------------------------

typedef __attribute__((ext_vector_type(8))) short bf16x8;
typedef __attribute__((ext_vector_type(4))) float f32x4;
typedef __attribute__((ext_vector_type(2))) float f32x2;

static __device__ __forceinline__ float bf_lo(unsigned u) {
    u <<= 16; return __builtin_bit_cast(float, u);
}
static __device__ __forceinline__ float bf_hi(unsigned u) {
    u &= 0xffff0000u; return __builtin_bit_cast(float, u);
}
static __device__ __forceinline__ unsigned short f2bf(float f) {
    __hip_bfloat16 b = __float2bfloat16(f);
    return __builtin_bit_cast(unsigned short, b);
}
static __device__ __forceinline__ unsigned packbf(float lo, float hi) {
    return (unsigned)f2bf(lo) | ((unsigned)f2bf(hi) << 16);
}

// ---- fp8 e4m3 encode/decode (HW converts on gfx950) ----
#if __has_builtin(__builtin_amdgcn_cvt_pk_fp8_f32) && __has_builtin(__builtin_amdgcn_cvt_pk_f32_fp8)
static __device__ __forceinline__ unsigned pk4_fp8(float a, float b, float c, float d) {
    int o = 0;
    o = __builtin_amdgcn_cvt_pk_fp8_f32(a, b, o, false);   // bytes 0,1
    o = __builtin_amdgcn_cvt_pk_fp8_f32(c, d, o, true);    // bytes 2,3
    return (unsigned)o;
}
// accumulate 8 fp8 channels (uint2) into acc[0..7]
static __device__ __forceinline__ void acc8_fp8(float* acc, uint2 v) {
    f32x2 a = __builtin_amdgcn_cvt_pk_f32_fp8((int)v.x, false);
    f32x2 b = __builtin_amdgcn_cvt_pk_f32_fp8((int)v.x, true);
    f32x2 c = __builtin_amdgcn_cvt_pk_f32_fp8((int)v.y, false);
    f32x2 d = __builtin_amdgcn_cvt_pk_f32_fp8((int)v.y, true);
    acc[0] += a[0]; acc[1] += a[1]; acc[2] += b[0]; acc[3] += b[1];
    acc[4] += c[0]; acc[5] += c[1]; acc[6] += d[0]; acc[7] += d[1];
}
#else
static __device__ __forceinline__ unsigned pk4_fp8(float a, float b, float c, float d) {
    __hip_fp8_e4m3 ea(a), eb(b), ec(c), ed(d);
    return (unsigned)ea.__x | ((unsigned)eb.__x << 8) |
           ((unsigned)ec.__x << 16) | ((unsigned)ed.__x << 24);
}
static __device__ __forceinline__ float f8dec_sw(unsigned v, int s) {
    __hip_fp8_e4m3 t; t.__x = (unsigned char)(v >> (s * 8)); return (float)t;
}
static __device__ __forceinline__ void acc8_fp8(float* acc, uint2 v) {
    acc[0] += f8dec_sw(v.x, 0); acc[1] += f8dec_sw(v.x, 1);
    acc[2] += f8dec_sw(v.x, 2); acc[3] += f8dec_sw(v.x, 3);
    acc[4] += f8dec_sw(v.y, 0); acc[5] += f8dec_sw(v.y, 1);
    acc[6] += f8dec_sw(v.y, 2); acc[7] += f8dec_sw(v.y, 3);
}
#endif

#define NRANGE   8
#define RANGE_W  6250      // N == 8*6250 exactly
#define PACKED_W 3125      // RANGE_W/2, two ushort counts per int
#define NSTRIPE  64
#define NHIST    (NRANGE * NSTRIPE)   // 512

static __device__ __forceinline__ int stripe_len(int E) {
    return ((E / NSTRIPE) + 3) & ~3;
}

// ---------------- MFMA dual GEMM-1 body (swapped operands) ----------------
// A[M][128] fp32 row-major; WTl/WTr[128][128] bf16 (=W^T).
// mfma(W-frag, x-frag): D lane l = out[row m0+(l&15)][ch ct*16+(l>>4)*4+reg].
// Pl = A@Wl as fp8 (uint store of 4 ch), Qr = A@Wr + bias as bf16 (ushort4).

template <int WPB>
static __device__ __forceinline__ void gemm1_body(
    int bid, int tid, const float* __restrict__ Av,
    const unsigned short* __restrict__ WTl,
    const unsigned short* __restrict__ WTr,
    const float* __restrict__ bias,
    unsigned char* __restrict__ Pl,
    unsigned short* __restrict__ Qr, int M) {
    const int wave = tid >> 6;
    const int lane = tid & 63;
    const int m0 = bid * (WPB * 16) + wave * 16;
    const int lr = lane & 15;
    const int lk = lane >> 4;

    int arow = m0 + lr;
    if (arow >= M) arow = M - 1;
    const bool rowok = (m0 + lr) < M;

    bf16x8 xf[4];
    {
        const float* Ab = Av + (size_t)arow * 128 + lk * 8;
#pragma unroll
        for (int s = 0; s < 4; ++s) {
            float4 v0 = *(const float4*)(Ab + s * 32);
            float4 v1 = *(const float4*)(Ab + s * 32 + 4);
            unsigned short t[8] = {f2bf(v0.x), f2bf(v0.y), f2bf(v0.z), f2bf(v0.w),
                                   f2bf(v1.x), f2bf(v1.y), f2bf(v1.z), f2bf(v1.w)};
            xf[s] = *(const bf16x8*)t;
        }
    }

#pragma unroll
    for (int ct = 0; ct < 8; ++ct) {
        const unsigned short* Bl = WTl + (size_t)(ct * 16 + lr) * 128 + lk * 8;
        const unsigned short* Br = WTr + (size_t)(ct * 16 + lr) * 128 + lk * 8;
        f32x4 accL = {0.f, 0.f, 0.f, 0.f};
        f32x4 accR = {0.f, 0.f, 0.f, 0.f};
#pragma unroll
        for (int s = 0; s < 4; ++s) {
            bf16x8 bl = *(const bf16x8*)(Bl + s * 32);
            bf16x8 br = *(const bf16x8*)(Br + s * 32);
            accL = __builtin_amdgcn_mfma_f32_16x16x32_bf16(bl, xf[s], accL, 0, 0, 0);
            accR = __builtin_amdgcn_mfma_f32_16x16x32_bf16(br, xf[s], accR, 0, 0, 0);
        }
        if (rowok) {
            float4 b4 = *(const float4*)(bias + ct * 16 + lk * 4);
            unsigned pk = pk4_fp8(accL[0], accL[1], accL[2], accL[3]);
            ushort4 oR;
            oR.x = f2bf(accR[0] + b4.x); oR.y = f2bf(accR[1] + b4.y);
            oR.z = f2bf(accR[2] + b4.z); oR.w = f2bf(accR[3] + b4.w);
            size_t base = (size_t)(m0 + lr) * 128 + ct * 16 + lk * 4;
            *(unsigned*)(Pl + base) = pk;
            *(ushort4*)(Qr + base) = oR;
        }
    }
}

// ---------------- D1: hist + packed-edge emit + weight prep ----------------

__global__ __launch_bounds__(512) void hist_wt_kernel(
    const int* __restrict__ src, const int* __restrict__ dst,
    int* __restrict__ hist, unsigned* __restrict__ packed, int E, int N,
    const float* __restrict__ W1l, const float* __restrict__ W1r,
    const float* __restrict__ W2l, const float* __restrict__ W2r,
    unsigned short* __restrict__ T1l, unsigned short* __restrict__ T1r,
    unsigned short* __restrict__ T2l, unsigned short* __restrict__ T2r) {
    __shared__ int lhist[PACKED_W];
    const int tid = threadIdx.x;
    if ((int)blockIdx.x >= NHIST) {
        int i = (blockIdx.x - NHIST) * 512 + tid;
        if (i < 16384) {
            int k = i >> 7, n = i & 127;
            T1l[n * 128 + k] = f2bf(W1l[i]);
            T1r[n * 128 + k] = f2bf(W1r[i]);
        } else if (i < 16384 + 8192) {
            int m = i - 16384;
            int k = m >> 6, n = m & 63;
            T2l[n * 128 + k] = f2bf(W2l[m]);
            T2r[n * 128 + k] = f2bf(W2r[m]);
        }
        return;
    }
    const int b = blockIdx.x;
    const int r = b & (NRANGE - 1);
    const int j = b >> 3;
    const int lo = r * RANGE_W;
    const int w = min(N - lo, RANGE_W);
    for (int i = tid; i < PACKED_W; i += 512) lhist[i] = 0;
    __syncthreads();
    const int stripe = stripe_len(E);
    const int s0 = j * stripe;
    const int s1 = min(E, s0 + stripe);
    for (int e = s0 + tid * 4; e < s1; e += 2048) {
        int4 dA = *(const int4*)(dst + e);
        if (r == 0) {
            int4 sA = *(const int4*)(src + e);
            uint4 pA;
            pA.x = ((unsigned)sA.x << 16) | (unsigned)dA.x;
            pA.y = ((unsigned)sA.y << 16) | (unsigned)dA.y;
            pA.z = ((unsigned)sA.z << 16) | (unsigned)dA.z;
            pA.w = ((unsigned)sA.w << 16) | (unsigned)dA.w;
            *(uint4*)(packed + e) = pA;
        }
        int a0 = dA.x - lo, a1 = dA.y - lo, a2 = dA.z - lo, a3 = dA.w - lo;
        if ((unsigned)a0 < (unsigned)w) atomicAdd(&lhist[a0 >> 1], 1u << ((a0 & 1) * 16));
        if ((unsigned)a1 < (unsigned)w) atomicAdd(&lhist[a1 >> 1], 1u << ((a1 & 1) * 16));
        if ((unsigned)a2 < (unsigned)w) atomicAdd(&lhist[a2 >> 1], 1u << ((a2 & 1) * 16));
        if ((unsigned)a3 < (unsigned)w) atomicAdd(&lhist[a3 >> 1], 1u << ((a3 & 1) * 16));
    }
    __syncthreads();
    int* gh = hist + ((size_t)r * NSTRIPE + j) * PACKED_W;
    for (int i = tid; i < PACKED_W; i += 512) gh[i] = lhist[i];
}

// ---------------- D2: scan ----------------

__global__ __launch_bounds__(256) void scan16_kernel(const int* __restrict__ hist,
                                                     int* __restrict__ row_start,
                                                     int* __restrict__ bsum, int N) {
    __shared__ int lds[256];
    int i = blockIdx.x * 256 + threadIdx.x;
    int v = 0;
    if (i < N) {
        int r = i / RANGE_W, loc = i - r * RANGE_W;
        const int* hp = hist + (size_t)r * NSTRIPE * PACKED_W + (loc >> 1);
        int sh = (loc & 1) * 16;
#pragma unroll 8
        for (int j = 0; j < NSTRIPE; ++j) v += (hp[j * PACKED_W] >> sh) & 0xffff;
    }
    lds[threadIdx.x] = v;
    __syncthreads();
    for (int off = 1; off < 256; off <<= 1) {
        int t = (threadIdx.x >= off) ? lds[threadIdx.x - off] : 0;
        __syncthreads();
        lds[threadIdx.x] += t;
        __syncthreads();
    }
    if (i < N) row_start[i] = lds[threadIdx.x] - v;
    if (threadIdx.x == 255) bsum[blockIdx.x] = lds[255];
}

// ---------------- D3: global prefix + absolute cursors ----------------

__global__ __launch_bounds__(256) void add_off_base_kernel(int* __restrict__ row_start,
                                                           const int* __restrict__ bsum,
                                                           const int* __restrict__ hist,
                                                           int* __restrict__ cur,
                                                           int N, int E) {
    __shared__ int lds[256];
    int b = blockIdx.x;
    lds[threadIdx.x] = (threadIdx.x < b) ? bsum[threadIdx.x] : 0;
    __syncthreads();
    for (int off = 128; off > 0; off >>= 1) {
        if (threadIdx.x < off) lds[threadIdx.x] += lds[threadIdx.x + off];
        __syncthreads();
    }
    int prefix = lds[0];
    int i = b * 256 + threadIdx.x;
    if (i < N) {
        int s = row_start[i] + prefix;
        row_start[i] = s;
        int r = i / RANGE_W, loc = i - r * RANGE_W;
        const int* hp = hist + (size_t)r * NSTRIPE * PACKED_W + (loc >> 1);
        int* cp = cur + (size_t)r * NSTRIPE * RANGE_W + loc;
        int sh = (loc & 1) * 16;
#pragma unroll 8
        for (int j = 0; j < NSTRIPE; ++j) {
            int h = (hp[j * PACKED_W] >> sh) & 0xffff;
            cp[j * RANGE_W] = s;
            s += h;
        }
    }
    if (b == 0 && threadIdx.x == 0) row_start[N] = E;
}

// ---------------- D4: scatter (packed edges) + GEMM-1 (backfill) ----------

__global__ __launch_bounds__(512) void scatter_gemm1_kernel(
    const unsigned* __restrict__ packed,
    const int* __restrict__ cur, unsigned short* __restrict__ csr_src,
    int E, int N,
    const float* __restrict__ x,
    const unsigned short* __restrict__ wt1l,
    const unsigned short* __restrict__ wt1r,
    const float* __restrict__ b1,
    unsigned char* __restrict__ Pl,
    unsigned short* __restrict__ Qr, int M) {
    __shared__ __align__(16) int lcur[RANGE_W];
    const int tid = threadIdx.x;
    if ((int)blockIdx.x >= NHIST) {
        gemm1_body<8>(blockIdx.x - NHIST, tid, x, wt1l, wt1r, b1, Pl, Qr, M);
        return;
    }
    const int b = blockIdx.x;
    const int r = b & (NRANGE - 1);
    const int j = b >> 3;
    const int lo = r * RANGE_W;
    const int w = min(N - lo, RANGE_W);
    const int* gb = cur + ((size_t)r * NSTRIPE + j) * RANGE_W;
    {
        int w4 = w & ~3;
        for (int i = tid * 4; i < w4; i += 2048)
            *(int4*)(&lcur[i]) = *(const int4*)(gb + i);
        for (int i = w4 + tid; i < w; i += 512) lcur[i] = gb[i];
    }
    __syncthreads();
    const int stripe = stripe_len(E);
    const int s0 = j * stripe;
    const int s1 = min(E, s0 + stripe);
    for (int e = s0 + tid * 4; e < s1; e += 2048) {
        uint4 pA = *(const uint4*)(packed + e);
        int a0 = (int)(pA.x & 0xffffu) - lo, a1 = (int)(pA.y & 0xffffu) - lo;
        int a2 = (int)(pA.z & 0xffffu) - lo, a3 = (int)(pA.w & 0xffffu) - lo;
        if ((unsigned)a0 < (unsigned)w) { int p = atomicAdd(&lcur[a0], 1); csr_src[p] = (unsigned short)(pA.x >> 16); }
        if ((unsigned)a1 < (unsigned)w) { int p = atomicAdd(&lcur[a1], 1); csr_src[p] = (unsigned short)(pA.y >> 16); }
        if ((unsigned)a2 < (unsigned)w) { int p = atomicAdd(&lcur[a2], 1); csr_src[p] = (unsigned short)(pA.z >> 16); }
        if ((unsigned)a3 < (unsigned)w) { int p = atomicAdd(&lcur[a3], 1); csr_src[p] = (unsigned short)(pA.w >> 16); }
    }
}

// ---------------- D5: agg1 + fused GEMM-2 (swapped operands) ----------------
// Gather (p fp8): 16 nodes/block, 4 nodes/wave, 16 lanes/node, 8ch(8B)/lane,
// 8-deep unroll. h bf16 in LDS [16][136]. MFMA: wave ct -> col-tile ct of
// g = h@W2_l (bf16) and r = h@W2_r + b2 (bf16), ushort4 stores.
__global__ __launch_bounds__(256) void agg1_gemm2_kernel(
    const unsigned char* __restrict__ p,
    const unsigned short* __restrict__ q,
    const int* __restrict__ row_start,
    const unsigned short* __restrict__ csr_src,
    const unsigned short* __restrict__ wt2l,
    const unsigned short* __restrict__ wt2r,
    const float* __restrict__ b2,
    unsigned short* __restrict__ g,
    unsigned short* __restrict__ rbuf, int N) {
    __shared__ unsigned short hsh[16][136];
    int tid = threadIdx.x;
    int nl = tid >> 4;
    int lane = tid & 15;
    int n = blockIdx.x * 16 + nl;
    int na = min(n, N - 1);
    int s0 = row_start[na], s1 = row_start[na + 1];
    float acc[8] = {};
    const unsigned char* pc = p + lane * 8;
    int e = s0;
    for (; e + 7 < s1; e += 8) {
        uint2 v0 = *(const uint2*)(pc + (size_t)csr_src[e]     * 128);
        uint2 v1 = *(const uint2*)(pc + (size_t)csr_src[e + 1] * 128);
        uint2 v2 = *(const uint2*)(pc + (size_t)csr_src[e + 2] * 128);
        uint2 v3 = *(const uint2*)(pc + (size_t)csr_src[e + 3] * 128);
        uint2 v4 = *(const uint2*)(pc + (size_t)csr_src[e + 4] * 128);
        uint2 v5 = *(const uint2*)(pc + (size_t)csr_src[e + 5] * 128);
        uint2 v6 = *(const uint2*)(pc + (size_t)csr_src[e + 6] * 128);
        uint2 v7 = *(const uint2*)(pc + (size_t)csr_src[e + 7] * 128);
        acc8_fp8(acc, v0); acc8_fp8(acc, v1); acc8_fp8(acc, v2); acc8_fp8(acc, v3);
        acc8_fp8(acc, v4); acc8_fp8(acc, v5); acc8_fp8(acc, v6); acc8_fp8(acc, v7);
    }
    for (; e + 3 < s1; e += 4) {
        uint2 v0 = *(const uint2*)(pc + (size_t)csr_src[e]     * 128);
        uint2 v1 = *(const uint2*)(pc + (size_t)csr_src[e + 1] * 128);
        uint2 v2 = *(const uint2*)(pc + (size_t)csr_src[e + 2] * 128);
        uint2 v3 = *(const uint2*)(pc + (size_t)csr_src[e + 3] * 128);
        acc8_fp8(acc, v0); acc8_fp8(acc, v1); acc8_fp8(acc, v2); acc8_fp8(acc, v3);
    }
    for (; e < s1; ++e) {
        uint2 v0 = *(const uint2*)(pc + (size_t)csr_src[e] * 128);
        acc8_fp8(acc, v0);
    }
    float inv = 1.0f / (float)max(s1 - s0, 1);
    uint4 qv = *(const uint4*)(q + (size_t)na * 128 + lane * 8);
    float hv[8];
    hv[0] = fmaxf(fmaf(acc[0], inv, bf_lo(qv.x)), 0.f);
    hv[1] = fmaxf(fmaf(acc[1], inv, bf_hi(qv.x)), 0.f);
    hv[2] = fmaxf(fmaf(acc[2], inv, bf_lo(qv.y)), 0.f);
    hv[3] = fmaxf(fmaf(acc[3], inv, bf_hi(qv.y)), 0.f);
    hv[4] = fmaxf(fmaf(acc[4], inv, bf_lo(qv.z)), 0.f);
    hv[5] = fmaxf(fmaf(acc[5], inv, bf_hi(qv.z)), 0.f);
    hv[6] = fmaxf(fmaf(acc[6], inv, bf_lo(qv.w)), 0.f);
    hv[7] = fmaxf(fmaf(acc[7], inv, bf_hi(qv.w)), 0.f);
    uint4 o;
    o.x = packbf(hv[0], hv[1]); o.y = packbf(hv[2], hv[3]);
    o.z = packbf(hv[4], hv[5]); o.w = packbf(hv[6], hv[7]);
    *(uint4*)(&hsh[nl][lane * 8]) = o;
    __syncthreads();

    const int wave = tid >> 6;
    const int wl = tid & 63;
    const int lr = wl & 15;
    const int lk = wl >> 4;
    const int gn = blockIdx.x * 16 + lr;
    const bool rowok = gn < N;
    const int ct = wave;
    f32x4 aL = {0.f, 0.f, 0.f, 0.f};
    f32x4 aR = {0.f, 0.f, 0.f, 0.f};
#pragma unroll
    for (int s = 0; s < 4; ++s) {
        bf16x8 hvv = *(const bf16x8*)(&hsh[lr][lk * 8 + s * 32]);
        bf16x8 bl = *(const bf16x8*)(wt2l + (size_t)(ct * 16 + lr) * 128 + lk * 8 + s * 32);
        bf16x8 br = *(const bf16x8*)(wt2r + (size_t)(ct * 16 + lr) * 128 + lk * 8 + s * 32);
        aL = __builtin_amdgcn_mfma_f32_16x16x32_bf16(bl, hvv, aL, 0, 0, 0);
        aR = __builtin_amdgcn_mfma_f32_16x16x32_bf16(br, hvv, aR, 0, 0, 0);
    }
    if (rowok) {
        float4 b4 = *(const float4*)(b2 + ct * 16 + lk * 4);
        ushort4 oL, oR;
        oL.x = f2bf(aL[0]); oL.y = f2bf(aL[1]); oL.z = f2bf(aL[2]); oL.w = f2bf(aL[3]);
        oR.x = f2bf(aR[0] + b4.x); oR.y = f2bf(aR[1] + b4.y);
        oR.z = f2bf(aR[2] + b4.z); oR.w = f2bf(aR[3] + b4.w);
        size_t base = (size_t)gn * 64 + ct * 16 + lk * 4;
        *(ushort4*)(g + base) = oL;
        *(ushort4*)(rbuf + base) = oR;
    }
}

// ---------------- D6: agg2 ----------------

__global__ __launch_bounds__(256) void agg2_kernel(const unsigned short* __restrict__ g,
                                                   const unsigned short* __restrict__ r,
                                                   const int* __restrict__ row_start,
                                                   const unsigned short* __restrict__ csr_src,
                                                   float* __restrict__ out, int N) {
    int tid = threadIdx.x;
    int n = blockIdx.x * 16 + (tid >> 4);
    int lane = tid & 15;
    if (n >= N) return;
    int s0 = row_start[n], s1 = row_start[n + 1];
    float acc[4] = {};
    const unsigned short* gc = g + lane * 4;
    int e = s0;
    for (; e + 7 < s1; e += 8) {
        uint2 v0 = *(const uint2*)(gc + (size_t)csr_src[e]     * 64);
        uint2 v1 = *(const uint2*)(gc + (size_t)csr_src[e + 1] * 64);
        uint2 v2 = *(const uint2*)(gc + (size_t)csr_src[e + 2] * 64);
        uint2 v3 = *(const uint2*)(gc + (size_t)csr_src[e + 3] * 64);
        uint2 v4 = *(const uint2*)(gc + (size_t)csr_src[e + 4] * 64);
        uint2 v5 = *(const uint2*)(gc + (size_t)csr_src[e + 5] * 64);
        uint2 v6 = *(const uint2*)(gc + (size_t)csr_src[e + 6] * 64);
        uint2 v7 = *(const uint2*)(gc + (size_t)csr_src[e + 7] * 64);
        acc[0] += ((bf_lo(v0.x) + bf_lo(v1.x)) + (bf_lo(v2.x) + bf_lo(v3.x)))
                + ((bf_lo(v4.x) + bf_lo(v5.x)) + (bf_lo(v6.x) + bf_lo(v7.x)));
        acc[1] += ((bf_hi(v0.x) + bf_hi(v1.x)) + (bf_hi(v2.x) + bf_hi(v3.x)))
                + ((bf_hi(v4.x) + bf_hi(v5.x)) + (bf_hi(v6.x) + bf_hi(v7.x)));
        acc[2] += ((bf_lo(v0.y) + bf_lo(v1.y)) + (bf_lo(v2.y) + bf_lo(v3.y)))
                + ((bf_lo(v4.y) + bf_lo(v5.y)) + (bf_lo(v6.y) + bf_lo(v7.y)));
        acc[3] += ((bf_hi(v0.y) + bf_hi(v1.y)) + (bf_hi(v2.y) + bf_hi(v3.y)))
                + ((bf_hi(v4.y) + bf_hi(v5.y)) + (bf_hi(v6.y) + bf_hi(v7.y)));
    }
    for (; e + 3 < s1; e += 4) {
        uint2 v0 = *(const uint2*)(gc + (size_t)csr_src[e]     * 64);
        uint2 v1 = *(const uint2*)(gc + (size_t)csr_src[e + 1] * 64);
        uint2 v2 = *(const uint2*)(gc + (size_t)csr_src[e + 2] * 64);
        uint2 v3 = *(const uint2*)(gc + (size_t)csr_src[e + 3] * 64);
        acc[0] += (bf_lo(v0.x) + bf_lo(v1.x)) + (bf_lo(v2.x) + bf_lo(v3.x));
        acc[1] += (bf_hi(v0.x) + bf_hi(v1.x)) + (bf_hi(v2.x) + bf_hi(v3.x));
        acc[2] += (bf_lo(v0.y) + bf_lo(v1.y)) + (bf_lo(v2.y) + bf_lo(v3.y));
        acc[3] += (bf_hi(v0.y) + bf_hi(v1.y)) + (bf_hi(v2.y) + bf_hi(v3.y));
    }
    for (; e < s1; ++e) {
        uint2 v0 = *(const uint2*)(gc + (size_t)csr_src[e] * 64);
        acc[0] += bf_lo(v0.x); acc[1] += bf_hi(v0.x);
        acc[2] += bf_lo(v0.y); acc[3] += bf_hi(v0.y);
    }
    float inv = 1.0f / (float)max(s1 - s0, 1);
    uint2 rv = *(const uint2*)(r + (size_t)n * 64 + lane * 4);
    float4 o;
    o.x = fmaf(acc[0], inv, bf_lo(rv.x));
    o.y = fmaf(acc[1], inv, bf_hi(rv.x));
    o.z = fmaf(acc[2], inv, bf_lo(rv.y));
    o.w = fmaf(acc[3], inv, bf_hi(rv.y));
    *(float4*)(out + (size_t)n * 64 + lane * 4) = o;
}

// ---------------------------------------------------------------------------

extern "C" void kernel_launch(void* const* d_in, const int* in_sizes, int n_in,
                              void* d_out, int out_size, void* d_ws, size_t ws_size,
                              hipStream_t stream) {
    const float* x    = (const float*)d_in[0];
    const int*   ei   = (const int*)d_in[1];
    const float* W1_l = (const float*)d_in[2];
    const float* b1   = (const float*)d_in[3];
    const float* W1_r = (const float*)d_in[4];
    const float* W2_l = (const float*)d_in[5];
    const float* b2   = (const float*)d_in[6];
    const float* W2_r = (const float*)d_in[7];

    const int N = in_sizes[0] / 128;   // 50000
    const int E = in_sizes[1] / 2;     // 800000
    const int* e_src = ei;
    const int* e_dst = ei + E;

    // ---- workspace layout ----
    char* ws = (char*)d_ws;
    auto align256 = [](size_t v) { return (v + 255) & ~(size_t)255; };
    size_t off = 0;
    int* row_start = (int*)(ws + off); off += align256((size_t)(N + 1) * 4);
    int* bsum      = (int*)(ws + off); off += align256(1024);
    int* hist      = (int*)(ws + off); off += align256((size_t)NRANGE * NSTRIPE * PACKED_W * 4);
    int* cur       = (int*)(ws + off); off += align256((size_t)NRANGE * NSTRIPE * RANGE_W * 4);
    unsigned* packed = (unsigned*)(ws + off); off += align256((size_t)E * 4);
    unsigned short* csr_src = (unsigned short*)(ws + off); off += align256((size_t)E * 2);
    unsigned char* p_f8   = (unsigned char*)(ws + off);  off += align256((size_t)N * 128);
    unsigned short* qr_bf = (unsigned short*)(ws + off); off += align256((size_t)N * 128 * 2);
    unsigned short* g_bf  = (unsigned short*)(ws + off); off += align256((size_t)N * 64 * 2);
    unsigned short* r_bf  = (unsigned short*)(ws + off); off += align256((size_t)N * 64 * 2);
    unsigned short* wt1l  = (unsigned short*)(ws + off); off += align256(128 * 128 * 2);
    unsigned short* wt1r  = (unsigned short*)(ws + off); off += align256(128 * 128 * 2);
    unsigned short* wt2l  = (unsigned short*)(ws + off); off += align256(128 * 64 * 2);
    unsigned short* wt2r  = (unsigned short*)(ws + off); off += align256(128 * 64 * 2);
    float* out = (float*)d_out;

    const int nb = (N + 255) / 256;
    const int nGemm1Wg = (N + 127) / 128;                 // 391 (128 rows/block)
    const int nWtWg = (16384 + 8192 + 511) / 512;         // 48

    // ---- D1: histogram + packed edges + weight prep (hist first, 512 thr) --
    hist_wt_kernel<<<NHIST + nWtWg, 512, 0, stream>>>(
        e_src, e_dst, hist, packed, E, N,
        W1_l, W1_r, W2_l, W2_r, wt1l, wt1r, wt2l, wt2r);
    // ---- D2/D3: CSR scan (no global atomics) ----
    scan16_kernel<<<nb, 256, 0, stream>>>(hist, row_start, bsum, N);
    add_off_base_kernel<<<nb, 256, 0, stream>>>(row_start, bsum, hist, cur, N, E);
    // ---- D4: scatter (packed) + GEMM-1 (p fp8, q+b1 bf16), scatter first ----
    scatter_gemm1_kernel<<<NHIST + nGemm1Wg, 512, 0, stream>>>(
        packed, cur, csr_src, E, N,
        x, wt1l, wt1r, b1, p_f8, qr_bf, N);
    // ---- D5: agg1 (fp8 gather) + fused GEMM-2 (g, r+b2 bf16) ----
    agg1_gemm2_kernel<<<(N + 15) / 16, 256, 0, stream>>>(
        p_f8, qr_bf, row_start, csr_src, wt2l, wt2r, b2, g_bf, r_bf, N);
    // ---- D6: agg2 ----
    agg2_kernel<<<(N + 15) / 16, 256, 0, stream>>>(g_bf, r_bf, row_start,
                                                   csr_src, out, N);
}